// Round 11
// baseline (242.185 us; speedup 1.0000x reference)
//
#include <hip/hip_runtime.h>
#include <math.h>

// OscillatoryAttention: B=2,S=2048,D=1024,H=16,dk=64. FP32 in/out, bf16 MFMA inside.
// R17: delete the P LDS round-trip. Swapped QK^T (mfma(K,Q)) puts each thread's 16
//      scores = one Q-row (l15) x 16 K-cols; with V token-permutation sigma
//      u = (jt>>1)*32 + quad*8 + (jt&1)*4 + r, those ARE the PV A-frag -> P stays
//      in registers (no Plb, no ds_write/ds_read, no lgkm chain). Coherence flips:
//      ci/si per-lane scalars, cj/sj per-(jt,quad) float4 from L1-hot global.
//      GEMM V-epilogue writes matching sigma. Rest = R14/R16 best config.

#define S_LEN 2048
#define NHEADS 16

typedef __attribute__((ext_vector_type(8))) short short8;
typedef __attribute__((ext_vector_type(4))) float floatx4;
typedef __attribute__((ext_vector_type(2))) float float2v;

__device__ inline unsigned short f2bf(float f) {
    union { float f; unsigned int i; } v; v.f = f;
    unsigned int u = v.i;
    return (unsigned short)((u + 0x7fffu + ((u >> 16) & 1u)) >> 16);
}
// pack two f32 -> packed bf16 u32 (truncation), low short = lo
__device__ inline unsigned int pack2_bf16(float hi, float lo) {
    union { float f; unsigned int u; } a, b; a.f = hi; b.f = lo;
    return __builtin_amdgcn_perm(a.u, b.u, 0x07060302u);
}
__device__ inline void async_copy16(const unsigned short* src, unsigned short* dst_lds) {
    __builtin_amdgcn_global_load_lds(
        (const __attribute__((address_space(1))) unsigned int*)(src),
        (__attribute__((address_space(3))) unsigned int*)(dst_lds), 16, 0, 0);
}

// ---------------- prep: phase+cvt (blocks 0..4095) | weight transpose (4096..5119)
__global__ __launch_bounds__(256) void prep_kernel(
    const float* __restrict__ x, const float* __restrict__ Wp,
    const float* __restrict__ bp,
    const float* __restrict__ w0, const float* __restrict__ w1,
    const float* __restrict__ w2, const float* __restrict__ w3,
    unsigned short* __restrict__ d0, unsigned short* __restrict__ d1,
    unsigned short* __restrict__ d2, unsigned short* __restrict__ d3,
    float* __restrict__ cosP, float* __restrict__ sinP,
    unsigned short* __restrict__ xb) {
    __shared__ __align__(16) unsigned short shmem[64 * 72];   // 9216 B union
    int t = threadIdx.x;
    if (blockIdx.x < 4096) {
        float* fb = reinterpret_cast<float*>(shmem);
        float* xs = fb;                                        // [1024] f32 x row
        float4* red4 = reinterpret_cast<float4*>(fb + 1024);   // [256] float4 partials
        int bid = blockIdx.x;
        int b = bid >> 11, s = bid & 2047;
        const float* xr = x + (size_t)bid * 1024;
        float4 xv = *reinterpret_cast<const float4*>(&xr[t * 4]);
        {
            uint2 o;
            o.x = (unsigned int)f2bf(xv.x) | ((unsigned int)f2bf(xv.y) << 16);
            o.y = (unsigned int)f2bf(xv.z) | ((unsigned int)f2bf(xv.w) << 16);
            *reinterpret_cast<uint2*>(&xb[(size_t)bid * 1024 + t * 4]) = o;
        }
        *reinterpret_cast<float4*>(&xs[t * 4]) = xv;
        __syncthreads();
        // coalesced GEMV: thread t owns h-block (t&3)*4, k rows i*64 + (t>>2)
        float f0 = 0.f, f1 = 0.f, f2 = 0.f, f3 = 0.f;
        int krow = t >> 2;
        const float4* wp4 = reinterpret_cast<const float4*>(Wp);
#pragma unroll
        for (int i = 0; i < 16; i++) {
            float4 wv = wp4[i * 256 + t];          // lane stride 16B: coalesced
            float xk = xs[i * 64 + krow];          // 4-lane broadcast, conflict-free
            f0 += xk * wv.x; f1 += xk * wv.y; f2 += xk * wv.z; f3 += xk * wv.w;
        }
        red4[t] = make_float4(f0, f1, f2, f3);
        __syncthreads();
        if (t < 16) {
            int b2 = t >> 2, comp = t & 3;
            const float* rf = fb + 1024;           // scalar view of red4
            float sum = bp[t];
#pragma unroll
            for (int j = 0; j < 64; j++) sum += rf[(4 * j + b2) * 4 + comp];
            float sv, cv;
            __sincosf(sum, &sv, &cv);
            size_t o = ((size_t)b * NHEADS + t) * S_LEN + s;
            cosP[o] = cv; sinP[o] = sv;
        }
    } else {
        unsigned short (*tile)[72] = reinterpret_cast<unsigned short (*)[72]>(shmem);
        int bid = blockIdx.x - 4096;
        int mat = bid >> 8;
        int tl  = bid & 255;
        int tr = tl >> 4, tc = tl & 15;
        const float* src    = (mat == 0) ? w0 : (mat == 1) ? w1 : (mat == 2) ? w2 : w3;
        unsigned short* dst = (mat == 0) ? d0 : (mat == 1) ? d1 : (mat == 2) ? d2 : d3;
        int col = t & 63, rbase = (t >> 6) * 16;
#pragma unroll
        for (int i = 0; i < 16; i++) {
            int row = rbase + i;
            tile[row][col] = f2bf(src[(size_t)(tr * 64 + row) * 1024 + tc * 64 + col]);
        }
        __syncthreads();
#pragma unroll
        for (int i = 0; i < 16; i++) {
            int row = rbase + i;
            dst[(size_t)(tc * 64 + row) * 1024 + tr * 64 + col] = tile[col][row];
        }
    }
}

// ---------------- GEMM (m97 recipe, baseline BK=32) ------------------------------
// mode 0: row-major fp32 out (+bias) -> of
// mode 1: N=3072 QKV: Q scaled 0.125*log2e -> (B,H,S,dk); K -> (B,H,S,dk);
//         V -> (B,H,dk,S) transposed, sigma-interleaved per 64-token chunk:
//         token j at short u = (jt>>1)*32 + ((j&15)>>2)*8 + (jt&1)*4 + (j&3), jt=j>>4.
template <int MT>
__global__ __launch_bounds__(256) void gemm_bt(
    const unsigned short* __restrict__ A, const unsigned short* __restrict__ BT,
    int N, int mode,
    const float* __restrict__ b0, const float* __restrict__ b1,
    const float* __restrict__ b2,
    unsigned short* __restrict__ o0, unsigned short* __restrict__ o1,
    unsigned short* __restrict__ o2, float* __restrict__ of) {
    __shared__ __align__(16) unsigned short As[MT * 32];
    __shared__ __align__(16) unsigned short Bs[128 * 32];
    const int K = 1024;
    const int MI = MT / 32;
    int t = threadIdx.x;
    int mBase = blockIdx.x * MT;
    int nBase = blockIdx.y * 128;
    int w = t >> 6, lane = t & 63, l15 = lane & 15, quad = lane >> 4;
    int wm = (w & 1) * (MT / 2), wn = (w >> 1) * 64;
    floatx4 acc[MI][4];
#pragma unroll
    for (int i = 0; i < MI; i++)
#pragma unroll
        for (int j = 0; j < 4; j++) acc[i][j] = (floatx4){0.f, 0.f, 0.f, 0.f};

    int arow = t >> 2, aseg = (t & 3) * 8;
    for (int k0 = 0; k0 < K; k0 += 32) {
        __syncthreads();
#pragma unroll
        for (int i = 0; i < MT / 64; i++)
            async_copy16(&A[(size_t)(mBase + i * 64 + arow) * K + k0 + aseg],
                         &As[(i * 64 + arow) * 32 + aseg]);
#pragma unroll
        for (int i = 0; i < 2; i++)
            async_copy16(&BT[(size_t)(nBase + i * 64 + arow) * K + k0 + aseg],
                         &Bs[(i * 64 + arow) * 32 + aseg]);
        __syncthreads();
        short8 af[MI], bfr[4];
#pragma unroll
        for (int mi = 0; mi < MI; mi++)
            af[mi] = *reinterpret_cast<const short8*>(&As[(wm + mi * 16 + l15) * 32 + quad * 8]);
#pragma unroll
        for (int ni = 0; ni < 4; ni++)
            bfr[ni] = *reinterpret_cast<const short8*>(&Bs[(wn + ni * 16 + l15) * 32 + quad * 8]);
#pragma unroll
        for (int mi = 0; mi < MI; mi++)
#pragma unroll
            for (int ni = 0; ni < 4; ni++)
                acc[mi][ni] = __builtin_amdgcn_mfma_f32_16x16x32_bf16(af[mi], bfr[ni], acc[mi][ni], 0, 0, 0);
    }

#pragma unroll
    for (int mi = 0; mi < MI; mi++) {
        int rowB = mBase + wm + mi * 16 + quad * 4;
#pragma unroll
        for (int ni = 0; ni < 4; ni++) {
            int col = nBase + wn + ni * 16 + l15;
            if (mode == 0) {
                float bias = b0[col];
#pragma unroll
                for (int r = 0; r < 4; r++) {
                    of[(size_t)(rowB + r) * N + col] = acc[mi][ni][r] + bias;
                }
            } else {
                int mat = col >> 10, nn = col & 1023;
                int h = nn >> 6, d = nn & 63;
                int b = rowB >> 11, sidx = rowB & 2047;
                if (mat == 2) {
                    float bv = b2[nn];
                    int jj = sidx & 63;                 // multiple of 4
                    size_t rowOff = ((size_t)((b * NHEADS + h) * 64 + d)) * S_LEN +
                                    (sidx & ~63);
#pragma unroll
                    for (int r = 0; r < 4; r++) {
                        int j2 = jj + r;
                        int jt = j2 >> 4;
                        int u = (jt >> 1) * 32 + ((j2 & 15) >> 2) * 8 + (jt & 1) * 4 + (j2 & 3);
                        o2[rowOff + u] = f2bf(acc[mi][ni][r] + bv);
                    }
                } else {
                    const float* bias  = (mat == 0) ? b0 : b1;
                    unsigned short* op = (mat == 0) ? o0 : o1;
                    float bv = bias[nn];
                    float scl = (mat == 0) ? 0.18033688f : 1.0f;  // dk^-0.5 * log2e
#pragma unroll
                    for (int r = 0; r < 4; r++) {
                        float cv = (acc[mi][ni][r] + bv) * scl;
                        op[(((size_t)b * NHEADS + h) * S_LEN + (sidx + r)) * 64 + d] = f2bf(cv);
                    }
                }
            }
        }
    }
}

// ---------------- flash attention, oscillatory coherence ------------------------
// grid = 256 blocks (1 per CU), 1024 thr (16 waves x 16 Q-rows = 256 Q-rows/block).
// XCD-swizzled. R17: swapped QK^T -> P register-resident (no Plb LDS round-trip).
__global__ __launch_bounds__(1024) void attn_kernel(
    const unsigned short* __restrict__ Qg, const unsigned short* __restrict__ Kg,
    const unsigned short* __restrict__ VTg,
    const float* __restrict__ cosP, const float* __restrict__ sinP,
    const float* __restrict__ alpha, unsigned short* __restrict__ ctx) {
    __shared__ __align__(16) unsigned short KsB[2][64 * 64];
    __shared__ __align__(16) unsigned short VtB[2][64 * 64];

    int x = blockIdx.x;                     // 0..255
    int bh = (x & 7) * 4 + (x >> 6);        // XCD (x%8) owns 4 consecutive bh groups
    int qt = (x >> 3) & 7;                  // 8 Q-tiles of 256 rows per bh
    int t = threadIdx.x, w = t >> 6, lane = t & 63, l15 = lane & 15, quad = lane >> 4;
    int m0 = qt * 256 + w * 16;
    size_t base = (size_t)bh * (S_LEN * 64);
    size_t phBase = (size_t)bh * S_LEN;
    const float L2E = 1.44269504f;

    // staging geometry: threads 0..511 own K bytes [16t,16t+16), 512..1023 own V
    int th = t & 511;
    int sj = th >> 3, sg = th & 7;
    int srot = ((sg - (sj & 7)) & 7) * 8;   // shorts: un-rotated global column
    bool stK = (t < 512);

    // Q frags; Q pre-scaled by 0.125*L2E. Used as B-operand (col = Q-row = l15).
    short8 qf[2];
#pragma unroll
    for (int c = 0; c < 2; c++)
        qf[c] = *reinterpret_cast<const short8*>(
            &Qg[base + (size_t)(m0 + l15) * 64 + c * 32 + quad * 8]);

    float alph = alpha[bh & 15] * L2E;
    // per-lane coherence coefficients for this thread's Q-row (m0 + l15)
    float ci = alph * cosP[phBase + m0 + l15];
    float si = alph * sinP[phBase + m0 + l15];
    float2v ci2 = (float2v){ci, ci}, si2 = (float2v){si, si};

    {   // stage kt=0 -> buf 0
        if (stK) async_copy16(&Kg[base + (size_t)sj * 64 + srot], &KsB[0][th * 8]);
        else     async_copy16(&VTg[base + (size_t)sj * S_LEN + srot], &VtB[0][th * 8]);
    }

    floatx4 oacc[4], lacc;
#pragma unroll
    for (int tt = 0; tt < 4; tt++) oacc[tt] = (floatx4){0.f, 0.f, 0.f, 0.f};
    lacc = (floatx4){0.f, 0.f, 0.f, 0.f};
    const short8 ones8 = {(short)0x3F80, (short)0x3F80, (short)0x3F80, (short)0x3F80,
                          (short)0x3F80, (short)0x3F80, (short)0x3F80, (short)0x3F80};

    // frag-read rotation
    int rot = l15 & 7;
    int cb0 = 16 * ((quad + rot) & 7);        // bytes, k-chunk c=0
    int cb1 = 16 * ((quad + 4 + rot) & 7);    // bytes, k-chunk c=1

    for (int kt = 0; kt < 32; kt++) {
        int p = kt & 1;
        __syncthreads();   // drains async copies for kt; buf p^1 free
        if (kt < 31) {
            int kn = kt + 1, pn = p ^ 1;
            if (stK) async_copy16(&Kg[base + (size_t)(kn * 64 + sj) * 64 + srot], &KsB[pn][th * 8]);
            else     async_copy16(&VTg[base + (size_t)sj * S_LEN + kn * 64 + srot], &VtB[pn][th * 8]);
        }

        // QK^T swapped: st[jt][r] = score[K-row kt*64+jt*16+quad*4+r][Q-row m0+l15]
        floatx4 st[4];
#pragma unroll
        for (int jt = 0; jt < 4; jt++) {
            const char* kr = (const char*)&KsB[p][(jt * 16 + l15) * 64];
            short8 kf0 = *reinterpret_cast<const short8*>(kr + cb0);
            short8 kf1 = *reinterpret_cast<const short8*>(kr + cb1);
            floatx4 s = (floatx4){0.f, 0.f, 0.f, 0.f};
            s = __builtin_amdgcn_mfma_f32_16x16x32_bf16(kf0, qf[0], s, 0, 0, 0);
            s = __builtin_amdgcn_mfma_f32_16x16x32_bf16(kf1, qf[1], s, 0, 0, 0);
            st[jt] = s;
        }

        // P = exp2(st + ci*cos(phi_j) + si*sin(phi_j)), packed in-register.
        // sigma: u = (jt>>1)*32 + quad*8 + (jt&1)*4 + r  ->  thread's 16 values
        // exactly fill its PV A-frags pf[0] (jt=0,1) and pf[1] (jt=2,3).
        union PW { unsigned int u[4]; short8 s8; };
        PW P0, P1;
#pragma unroll
        for (int jt = 0; jt < 4; jt++) {
            const float* cpb = &cosP[phBase + kt * 64 + jt * 16 + quad * 4];
            const float* spb = &sinP[phBase + kt * 64 + jt * 16 + quad * 4];
            float4 cj = *reinterpret_cast<const float4*>(cpb);
            float4 sjv = *reinterpret_cast<const float4*>(spb);
            float2v st01 = (float2v){st[jt][0], st[jt][1]};
            float2v st23 = (float2v){st[jt][2], st[jt][3]};
            float2v c01 = (float2v){cj.x, cj.y}, c23 = (float2v){cj.z, cj.w};
            float2v s01 = (float2v){sjv.x, sjv.y}, s23 = (float2v){sjv.z, sjv.w};
            float2v a01 = si2 * s01 + (ci2 * c01 + st01);
            float2v a23 = si2 * s23 + (ci2 * c23 + st23);
            unsigned int wA = pack2_bf16(__builtin_amdgcn_exp2f(a01.y),
                                         __builtin_amdgcn_exp2f(a01.x));
            unsigned int wB = pack2_bf16(__builtin_amdgcn_exp2f(a23.y),
                                         __builtin_amdgcn_exp2f(a23.x));
            if (jt == 0)      { P0.u[0] = wA; P0.u[1] = wB; }
            else if (jt == 1) { P0.u[2] = wA; P0.u[3] = wB; }
            else if (jt == 2) { P1.u[0] = wA; P1.u[1] = wB; }
            else              { P1.u[2] = wA; P1.u[3] = wB; }
        }

        // O += P @ V; l += P @ ones   (V stored with matching sigma)
#pragma unroll
        for (int c = 0; c < 2; c++) {
            short8 pf = c ? P1.s8 : P0.s8;
            int cb = c ? cb1 : cb0;
#pragma unroll
            for (int tt = 0; tt < 4; tt++) {
                const char* vr = (const char*)&VtB[p][(tt * 16 + l15) * 64];
                short8 vf = *reinterpret_cast<const short8*>(vr + cb);
                oacc[tt] = __builtin_amdgcn_mfma_f32_16x16x32_bf16(pf, vf, oacc[tt], 0, 0, 0);
            }
            lacc = __builtin_amdgcn_mfma_f32_16x16x32_bf16(pf, ones8, lacc, 0, 0, 0);
        }
    }

    // epilogue: normalize rows by l and write ctx[b][s][h*64+d]
    int b = bh >> 4, h = bh & 15;
    float inv[4];
#pragma unroll
    for (int r = 0; r < 4; r++) inv[r] = 1.0f / lacc[r];
#pragma unroll
    for (int tt = 0; tt < 4; tt++)
#pragma unroll
        for (int r = 0; r < 4; r++) {
            int srow = m0 + quad * 4 + r;
            ctx[((size_t)(b * S_LEN + srow)) * 1024 + h * 64 + tt * 16 + l15] =
                f2bf(oacc[tt][r] * inv[r]);
        }
}

extern "C" void kernel_launch(void* const* d_in, const int* in_sizes, int n_in,
                              void* d_out, int out_size, void* d_ws, size_t ws_size,
                              hipStream_t stream) {
    const float* x     = (const float*)d_in[0];
    const float* Wq    = (const float*)d_in[1];
    const float* bq    = (const float*)d_in[2];
    const float* Wk    = (const float*)d_in[3];
    const float* bk    = (const float*)d_in[4];
    const float* Wv    = (const float*)d_in[5];
    const float* bv    = (const float*)d_in[6];
    const float* Wo    = (const float*)d_in[7];
    const float* bo    = (const float*)d_in[8];
    const float* Wp    = (const float*)d_in[9];
    const float* bp    = (const float*)d_in[10];
    const float* alpha = (const float*)d_in[11];
    float* out = (float*)d_out;

    const size_t MB = 1048576;
    char* ws = (char*)d_ws;
    unsigned short* WT   = (unsigned short*)(ws);             // 3072x1024 bf16
    unsigned short* WoT  = (unsigned short*)(ws + 6 * MB);    // 1024x1024 bf16
    unsigned short* xb   = (unsigned short*)(ws + 8 * MB);    // (B,S,D) bf16
    unsigned short* ctx  = (unsigned short*)(ws + 8 * MB);    // aliases xb
    unsigned short* Qw   = (unsigned short*)(ws + 16 * MB);   // (B,H,S,dk), pre-scaled
    unsigned short* Kw   = (unsigned short*)(ws + 24 * MB);   // (B,H,S,dk)
    unsigned short* VTg  = (unsigned short*)(ws + 32 * MB);   // (B,H,dk,S) sigma-interleaved
    float* cosP          = (float*)(ws + 40 * MB);
    float* sinP          = (float*)(ws + 40 * MB + 262144);

    prep_kernel<<<dim3(5120), dim3(256), 0, stream>>>(
        x, Wp, bp, Wq, Wk, Wv, Wo,
        WT, WT + 1048576, WT + 2097152, WoT, cosP, sinP, xb);
    gemm_bt<128><<<dim3(32, 24), dim3(256), 0, stream>>>(
        xb, WT, 3072, 1, bq, bk, bv, Qw, Kw, VTg, (float*)nullptr);
    attn_kernel<<<dim3(256), dim3(1024), 0, stream>>>(
        Qw, Kw, VTg, cosP, sinP, alpha, ctx);
    gemm_bt<64><<<dim3(64, 8), dim3(256), 0, stream>>>(
        ctx, WoT, 1024, 0, bo, bo, bo,
        (unsigned short*)nullptr, (unsigned short*)nullptr,
        (unsigned short*)nullptr, out);
}

// Round 12
// 229.124 us; speedup vs baseline: 1.0570x; 1.0570x over previous
//
#include <hip/hip_runtime.h>
#include <math.h>

// OscillatoryAttention: B=2,S=2048,D=1024,H=16,dk=64. FP32 in/out, bf16 MFMA inside.
// R18: R17 (register-P via swapped QK^T; bank-conflicts 0) + fix its regression:
//      R17's cos/sin loads were issued AFTER the staging global_load_lds, and vmcnt
//      is in-order -> waiting for cos/sin mid-iteration drained the next tile's
//      staging too (75us). Now cos/sin for kt+1 are prefetched into REGISTERS during
//      iter kt; the compiler's vmcnt(0)-before-barrier drains them for free, so the
//      iteration body has no mid-iter VMEM wait at all.

#define S_LEN 2048
#define NHEADS 16

typedef __attribute__((ext_vector_type(8))) short short8;
typedef __attribute__((ext_vector_type(4))) float floatx4;
typedef __attribute__((ext_vector_type(2))) float float2v;

__device__ inline unsigned short f2bf(float f) {
    union { float f; unsigned int i; } v; v.f = f;
    unsigned int u = v.i;
    return (unsigned short)((u + 0x7fffu + ((u >> 16) & 1u)) >> 16);
}
// pack two f32 -> packed bf16 u32 (truncation), low short = lo
__device__ inline unsigned int pack2_bf16(float hi, float lo) {
    union { float f; unsigned int u; } a, b; a.f = hi; b.f = lo;
    return __builtin_amdgcn_perm(a.u, b.u, 0x07060302u);
}
__device__ inline void async_copy16(const unsigned short* src, unsigned short* dst_lds) {
    __builtin_amdgcn_global_load_lds(
        (const __attribute__((address_space(1))) unsigned int*)(src),
        (__attribute__((address_space(3))) unsigned int*)(dst_lds), 16, 0, 0);
}

// ---------------- prep: phase+cvt (blocks 0..4095) | weight transpose (4096..5119)
__global__ __launch_bounds__(256) void prep_kernel(
    const float* __restrict__ x, const float* __restrict__ Wp,
    const float* __restrict__ bp,
    const float* __restrict__ w0, const float* __restrict__ w1,
    const float* __restrict__ w2, const float* __restrict__ w3,
    unsigned short* __restrict__ d0, unsigned short* __restrict__ d1,
    unsigned short* __restrict__ d2, unsigned short* __restrict__ d3,
    float* __restrict__ cosP, float* __restrict__ sinP,
    unsigned short* __restrict__ xb) {
    __shared__ __align__(16) unsigned short shmem[64 * 72];   // 9216 B union
    int t = threadIdx.x;
    if (blockIdx.x < 4096) {
        float* fb = reinterpret_cast<float*>(shmem);
        float* xs = fb;                                        // [1024] f32 x row
        float4* red4 = reinterpret_cast<float4*>(fb + 1024);   // [256] float4 partials
        int bid = blockIdx.x;
        int b = bid >> 11, s = bid & 2047;
        const float* xr = x + (size_t)bid * 1024;
        float4 xv = *reinterpret_cast<const float4*>(&xr[t * 4]);
        {
            uint2 o;
            o.x = (unsigned int)f2bf(xv.x) | ((unsigned int)f2bf(xv.y) << 16);
            o.y = (unsigned int)f2bf(xv.z) | ((unsigned int)f2bf(xv.w) << 16);
            *reinterpret_cast<uint2*>(&xb[(size_t)bid * 1024 + t * 4]) = o;
        }
        *reinterpret_cast<float4*>(&xs[t * 4]) = xv;
        __syncthreads();
        // coalesced GEMV: thread t owns h-block (t&3)*4, k rows i*64 + (t>>2)
        float f0 = 0.f, f1 = 0.f, f2 = 0.f, f3 = 0.f;
        int krow = t >> 2;
        const float4* wp4 = reinterpret_cast<const float4*>(Wp);
#pragma unroll
        for (int i = 0; i < 16; i++) {
            float4 wv = wp4[i * 256 + t];          // lane stride 16B: coalesced
            float xk = xs[i * 64 + krow];          // 4-lane broadcast, conflict-free
            f0 += xk * wv.x; f1 += xk * wv.y; f2 += xk * wv.z; f3 += xk * wv.w;
        }
        red4[t] = make_float4(f0, f1, f2, f3);
        __syncthreads();
        if (t < 16) {
            int b2 = t >> 2, comp = t & 3;
            const float* rf = fb + 1024;           // scalar view of red4
            float sum = bp[t];
#pragma unroll
            for (int j = 0; j < 64; j++) sum += rf[(4 * j + b2) * 4 + comp];
            float sv, cv;
            __sincosf(sum, &sv, &cv);
            size_t o = ((size_t)b * NHEADS + t) * S_LEN + s;
            cosP[o] = cv; sinP[o] = sv;
        }
    } else {
        unsigned short (*tile)[72] = reinterpret_cast<unsigned short (*)[72]>(shmem);
        int bid = blockIdx.x - 4096;
        int mat = bid >> 8;
        int tl  = bid & 255;
        int tr = tl >> 4, tc = tl & 15;
        const float* src    = (mat == 0) ? w0 : (mat == 1) ? w1 : (mat == 2) ? w2 : w3;
        unsigned short* dst = (mat == 0) ? d0 : (mat == 1) ? d1 : (mat == 2) ? d2 : d3;
        int col = t & 63, rbase = (t >> 6) * 16;
#pragma unroll
        for (int i = 0; i < 16; i++) {
            int row = rbase + i;
            tile[row][col] = f2bf(src[(size_t)(tr * 64 + row) * 1024 + tc * 64 + col]);
        }
        __syncthreads();
#pragma unroll
        for (int i = 0; i < 16; i++) {
            int row = rbase + i;
            dst[(size_t)(tc * 64 + row) * 1024 + tr * 64 + col] = tile[col][row];
        }
    }
}

// ---------------- GEMM (m97 recipe, baseline BK=32) ------------------------------
// mode 0: row-major fp32 out (+bias) -> of
// mode 1: N=3072 QKV: Q scaled 0.125*log2e -> (B,H,S,dk); K -> (B,H,S,dk);
//         V -> (B,H,dk,S) transposed, sigma-interleaved per 64-token chunk:
//         token j at short u = (jt>>1)*32 + ((j&15)>>2)*8 + (jt&1)*4 + (j&3), jt=j>>4.
template <int MT>
__global__ __launch_bounds__(256) void gemm_bt(
    const unsigned short* __restrict__ A, const unsigned short* __restrict__ BT,
    int N, int mode,
    const float* __restrict__ b0, const float* __restrict__ b1,
    const float* __restrict__ b2,
    unsigned short* __restrict__ o0, unsigned short* __restrict__ o1,
    unsigned short* __restrict__ o2, float* __restrict__ of) {
    __shared__ __align__(16) unsigned short As[MT * 32];
    __shared__ __align__(16) unsigned short Bs[128 * 32];
    const int K = 1024;
    const int MI = MT / 32;
    int t = threadIdx.x;
    int mBase = blockIdx.x * MT;
    int nBase = blockIdx.y * 128;
    int w = t >> 6, lane = t & 63, l15 = lane & 15, quad = lane >> 4;
    int wm = (w & 1) * (MT / 2), wn = (w >> 1) * 64;
    floatx4 acc[MI][4];
#pragma unroll
    for (int i = 0; i < MI; i++)
#pragma unroll
        for (int j = 0; j < 4; j++) acc[i][j] = (floatx4){0.f, 0.f, 0.f, 0.f};

    int arow = t >> 2, aseg = (t & 3) * 8;
    for (int k0 = 0; k0 < K; k0 += 32) {
        __syncthreads();
#pragma unroll
        for (int i = 0; i < MT / 64; i++)
            async_copy16(&A[(size_t)(mBase + i * 64 + arow) * K + k0 + aseg],
                         &As[(i * 64 + arow) * 32 + aseg]);
#pragma unroll
        for (int i = 0; i < 2; i++)
            async_copy16(&BT[(size_t)(nBase + i * 64 + arow) * K + k0 + aseg],
                         &Bs[(i * 64 + arow) * 32 + aseg]);
        __syncthreads();
        short8 af[MI], bfr[4];
#pragma unroll
        for (int mi = 0; mi < MI; mi++)
            af[mi] = *reinterpret_cast<const short8*>(&As[(wm + mi * 16 + l15) * 32 + quad * 8]);
#pragma unroll
        for (int ni = 0; ni < 4; ni++)
            bfr[ni] = *reinterpret_cast<const short8*>(&Bs[(wn + ni * 16 + l15) * 32 + quad * 8]);
#pragma unroll
        for (int mi = 0; mi < MI; mi++)
#pragma unroll
            for (int ni = 0; ni < 4; ni++)
                acc[mi][ni] = __builtin_amdgcn_mfma_f32_16x16x32_bf16(af[mi], bfr[ni], acc[mi][ni], 0, 0, 0);
    }

#pragma unroll
    for (int mi = 0; mi < MI; mi++) {
        int rowB = mBase + wm + mi * 16 + quad * 4;
#pragma unroll
        for (int ni = 0; ni < 4; ni++) {
            int col = nBase + wn + ni * 16 + l15;
            if (mode == 0) {
                float bias = b0[col];
#pragma unroll
                for (int r = 0; r < 4; r++) {
                    of[(size_t)(rowB + r) * N + col] = acc[mi][ni][r] + bias;
                }
            } else {
                int mat = col >> 10, nn = col & 1023;
                int h = nn >> 6, d = nn & 63;
                int b = rowB >> 11, sidx = rowB & 2047;
                if (mat == 2) {
                    float bv = b2[nn];
                    int jj = sidx & 63;                 // multiple of 4
                    size_t rowOff = ((size_t)((b * NHEADS + h) * 64 + d)) * S_LEN +
                                    (sidx & ~63);
#pragma unroll
                    for (int r = 0; r < 4; r++) {
                        int j2 = jj + r;
                        int jt = j2 >> 4;
                        int u = (jt >> 1) * 32 + ((j2 & 15) >> 2) * 8 + (jt & 1) * 4 + (j2 & 3);
                        o2[rowOff + u] = f2bf(acc[mi][ni][r] + bv);
                    }
                } else {
                    const float* bias  = (mat == 0) ? b0 : b1;
                    unsigned short* op = (mat == 0) ? o0 : o1;
                    float bv = bias[nn];
                    float scl = (mat == 0) ? 0.18033688f : 1.0f;  // dk^-0.5 * log2e
#pragma unroll
                    for (int r = 0; r < 4; r++) {
                        float cv = (acc[mi][ni][r] + bv) * scl;
                        op[(((size_t)b * NHEADS + h) * S_LEN + (sidx + r)) * 64 + d] = f2bf(cv);
                    }
                }
            }
        }
    }
}

// ---------------- flash attention, oscillatory coherence ------------------------
// grid = 256 blocks (1 per CU), 1024 thr (16 waves x 16 Q-rows = 256 Q-rows/block).
// XCD-swizzled. Register-P (swapped QK^T) + cos/sin register prefetch one tile ahead
// (drained for free by the pre-barrier vmcnt(0)) -> no mid-iteration VMEM wait.
__global__ __launch_bounds__(1024) void attn_kernel(
    const unsigned short* __restrict__ Qg, const unsigned short* __restrict__ Kg,
    const unsigned short* __restrict__ VTg,
    const float* __restrict__ cosP, const float* __restrict__ sinP,
    const float* __restrict__ alpha, unsigned short* __restrict__ ctx) {
    __shared__ __align__(16) unsigned short KsB[2][64 * 64];
    __shared__ __align__(16) unsigned short VtB[2][64 * 64];

    int x = blockIdx.x;                     // 0..255
    int bh = (x & 7) * 4 + (x >> 6);        // XCD (x%8) owns 4 consecutive bh groups
    int qt = (x >> 3) & 7;                  // 8 Q-tiles of 256 rows per bh
    int t = threadIdx.x, w = t >> 6, lane = t & 63, l15 = lane & 15, quad = lane >> 4;
    int m0 = qt * 256 + w * 16;
    size_t base = (size_t)bh * (S_LEN * 64);
    size_t phBase = (size_t)bh * S_LEN;
    const float L2E = 1.44269504f;

    // staging geometry: threads 0..511 own K bytes [16t,16t+16), 512..1023 own V
    int th = t & 511;
    int sj = th >> 3, sg = th & 7;
    int srot = ((sg - (sj & 7)) & 7) * 8;   // shorts: un-rotated global column
    bool stK = (t < 512);

    // Q frags; Q pre-scaled by 0.125*L2E. Used as B-operand (col = Q-row = l15).
    short8 qf[2];
#pragma unroll
    for (int c = 0; c < 2; c++)
        qf[c] = *reinterpret_cast<const short8*>(
            &Qg[base + (size_t)(m0 + l15) * 64 + c * 32 + quad * 8]);

    float alph = alpha[bh & 15] * L2E;
    // per-lane coherence coefficients for this thread's Q-row (m0 + l15)
    float ci = alph * cosP[phBase + m0 + l15];
    float si = alph * sinP[phBase + m0 + l15];
    float2v ci2 = (float2v){ci, ci}, si2 = (float2v){si, si};

    {   // stage kt=0 -> buf 0
        if (stK) async_copy16(&Kg[base + (size_t)sj * 64 + srot], &KsB[0][th * 8]);
        else     async_copy16(&VTg[base + (size_t)sj * S_LEN + srot], &VtB[0][th * 8]);
    }

    // cos/sin register prefetch: cjR/sjR hold tile kt's values (float4 per jt)
    float4 cjR[4], sjR[4];
#pragma unroll
    for (int jt = 0; jt < 4; jt++) {
        cjR[jt] = *reinterpret_cast<const float4*>(&cosP[phBase + jt * 16 + quad * 4]);
        sjR[jt] = *reinterpret_cast<const float4*>(&sinP[phBase + jt * 16 + quad * 4]);
    }

    floatx4 oacc[4], lacc;
#pragma unroll
    for (int tt = 0; tt < 4; tt++) oacc[tt] = (floatx4){0.f, 0.f, 0.f, 0.f};
    lacc = (floatx4){0.f, 0.f, 0.f, 0.f};
    const short8 ones8 = {(short)0x3F80, (short)0x3F80, (short)0x3F80, (short)0x3F80,
                          (short)0x3F80, (short)0x3F80, (short)0x3F80, (short)0x3F80};

    // frag-read rotation
    int rot = l15 & 7;
    int cb0 = 16 * ((quad + rot) & 7);        // bytes, k-chunk c=0
    int cb1 = 16 * ((quad + 4 + rot) & 7);    // bytes, k-chunk c=1

    for (int kt = 0; kt < 32; kt++) {
        int p = kt & 1;
        __syncthreads();   // staging for kt complete; all prior VMEM (incl. prefetch) drained
        float4 cjN[4], sjN[4];
        if (kt < 31) {
            int kn = kt + 1, pn = p ^ 1;
            if (stK) async_copy16(&Kg[base + (size_t)(kn * 64 + sj) * 64 + srot], &KsB[pn][th * 8]);
            else     async_copy16(&VTg[base + (size_t)sj * S_LEN + kn * 64 + srot], &VtB[pn][th * 8]);
            // prefetch cos/sin for kt+1 into registers (used NEXT iter; the
            // pre-barrier vmcnt(0) drains them for free)
            const float* cpb = &cosP[phBase + kn * 64 + quad * 4];
            const float* spb = &sinP[phBase + kn * 64 + quad * 4];
#pragma unroll
            for (int jt = 0; jt < 4; jt++) {
                cjN[jt] = *reinterpret_cast<const float4*>(cpb + jt * 16);
                sjN[jt] = *reinterpret_cast<const float4*>(spb + jt * 16);
            }
        }

        // QK^T swapped: st[jt][r] = score[K-tok kt*64+jt*16+quad*4+r][Q-row m0+l15]
        floatx4 st[4];
#pragma unroll
        for (int jt = 0; jt < 4; jt++) {
            const char* kr = (const char*)&KsB[p][(jt * 16 + l15) * 64];
            short8 kf0 = *reinterpret_cast<const short8*>(kr + cb0);
            short8 kf1 = *reinterpret_cast<const short8*>(kr + cb1);
            floatx4 s = (floatx4){0.f, 0.f, 0.f, 0.f};
            s = __builtin_amdgcn_mfma_f32_16x16x32_bf16(kf0, qf[0], s, 0, 0, 0);
            s = __builtin_amdgcn_mfma_f32_16x16x32_bf16(kf1, qf[1], s, 0, 0, 0);
            st[jt] = s;
        }

        // P = exp2(st + ci*cos(phi_j) + si*sin(phi_j)), packed in-register.
        // sigma: u = (jt>>1)*32 + quad*8 + (jt&1)*4 + r -> thread's 16 values are
        // exactly its PV A-frags P0 (jt=0,1) and P1 (jt=2,3).
        union PW { unsigned int u[4]; short8 s8; };
        PW P0, P1;
#pragma unroll
        for (int jt = 0; jt < 4; jt++) {
            float2v st01 = (float2v){st[jt][0], st[jt][1]};
            float2v st23 = (float2v){st[jt][2], st[jt][3]};
            float2v c01 = (float2v){cjR[jt].x, cjR[jt].y};
            float2v c23 = (float2v){cjR[jt].z, cjR[jt].w};
            float2v s01 = (float2v){sjR[jt].x, sjR[jt].y};
            float2v s23 = (float2v){sjR[jt].z, sjR[jt].w};
            float2v a01 = si2 * s01 + (ci2 * c01 + st01);
            float2v a23 = si2 * s23 + (ci2 * c23 + st23);
            unsigned int wA = pack2_bf16(__builtin_amdgcn_exp2f(a01.y),
                                         __builtin_amdgcn_exp2f(a01.x));
            unsigned int wB = pack2_bf16(__builtin_amdgcn_exp2f(a23.y),
                                         __builtin_amdgcn_exp2f(a23.x));
            if (jt == 0)      { P0.u[0] = wA; P0.u[1] = wB; }
            else if (jt == 1) { P0.u[2] = wA; P0.u[3] = wB; }
            else if (jt == 2) { P1.u[0] = wA; P1.u[1] = wB; }
            else              { P1.u[2] = wA; P1.u[3] = wB; }
        }

        // O += P @ V; l += P @ ones   (V stored with matching sigma)
#pragma unroll
        for (int c = 0; c < 2; c++) {
            short8 pf = c ? P1.s8 : P0.s8;
            int cb = c ? cb1 : cb0;
#pragma unroll
            for (int tt = 0; tt < 4; tt++) {
                const char* vr = (const char*)&VtB[p][(tt * 16 + l15) * 64];
                short8 vf = *reinterpret_cast<const short8*>(vr + cb);
                oacc[tt] = __builtin_amdgcn_mfma_f32_16x16x32_bf16(pf, vf, oacc[tt], 0, 0, 0);
            }
            lacc = __builtin_amdgcn_mfma_f32_16x16x32_bf16(pf, ones8, lacc, 0, 0, 0);
        }

        if (kt < 31) {
#pragma unroll
            for (int jt = 0; jt < 4; jt++) { cjR[jt] = cjN[jt]; sjR[jt] = sjN[jt]; }
        }
    }

    // epilogue: normalize rows by l and write ctx[b][s][h*64+d]
    int b = bh >> 4, h = bh & 15;
    float inv[4];
#pragma unroll
    for (int r = 0; r < 4; r++) inv[r] = 1.0f / lacc[r];
#pragma unroll
    for (int tt = 0; tt < 4; tt++)
#pragma unroll
        for (int r = 0; r < 4; r++) {
            int srow = m0 + quad * 4 + r;
            ctx[((size_t)(b * S_LEN + srow)) * 1024 + h * 64 + tt * 16 + l15] =
                f2bf(oacc[tt][r] * inv[r]);
        }
}

extern "C" void kernel_launch(void* const* d_in, const int* in_sizes, int n_in,
                              void* d_out, int out_size, void* d_ws, size_t ws_size,
                              hipStream_t stream) {
    const float* x     = (const float*)d_in[0];
    const float* Wq    = (const float*)d_in[1];
    const float* bq    = (const float*)d_in[2];
    const float* Wk    = (const float*)d_in[3];
    const float* bk    = (const float*)d_in[4];
    const float* Wv    = (const float*)d_in[5];
    const float* bv    = (const float*)d_in[6];
    const float* Wo    = (const float*)d_in[7];
    const float* bo    = (const float*)d_in[8];
    const float* Wp    = (const float*)d_in[9];
    const float* bp    = (const float*)d_in[10];
    const float* alpha = (const float*)d_in[11];
    float* out = (float*)d_out;

    const size_t MB = 1048576;
    char* ws = (char*)d_ws;
    unsigned short* WT   = (unsigned short*)(ws);             // 3072x1024 bf16
    unsigned short* WoT  = (unsigned short*)(ws + 6 * MB);    // 1024x1024 bf16
    unsigned short* xb   = (unsigned short*)(ws + 8 * MB);    // (B,S,D) bf16
    unsigned short* ctx  = (unsigned short*)(ws + 8 * MB);    // aliases xb
    unsigned short* Qw   = (unsigned short*)(ws + 16 * MB);   // (B,H,S,dk), pre-scaled
    unsigned short* Kw   = (unsigned short*)(ws + 24 * MB);   // (B,H,S,dk)
    unsigned short* VTg  = (unsigned short*)(ws + 32 * MB);   // (B,H,dk,S) sigma-interleaved
    float* cosP          = (float*)(ws + 40 * MB);
    float* sinP          = (float*)(ws + 40 * MB + 262144);

    prep_kernel<<<dim3(5120), dim3(256), 0, stream>>>(
        x, Wp, bp, Wq, Wk, Wv, Wo,
        WT, WT + 1048576, WT + 2097152, WoT, cosP, sinP, xb);
    gemm_bt<128><<<dim3(32, 24), dim3(256), 0, stream>>>(
        xb, WT, 3072, 1, bq, bk, bv, Qw, Kw, VTg, (float*)nullptr);
    attn_kernel<<<dim3(256), dim3(1024), 0, stream>>>(
        Qw, Kw, VTg, cosP, sinP, alpha, ctx);
    gemm_bt<64><<<dim3(64, 8), dim3(256), 0, stream>>>(
        ctx, WoT, 1024, 0, bo, bo, bo,
        (unsigned short*)nullptr, (unsigned short*)nullptr,
        (unsigned short*)nullptr, out);
}

// Round 13
// 222.184 us; speedup vs baseline: 1.0900x; 1.0312x over previous
//
#include <hip/hip_runtime.h>
#include <math.h>

// OscillatoryAttention: B=2,S=2048,D=1024,H=16,dk=64. FP32 in/out, bf16 MFMA inside.
// R19: synthesis. Register-P (swapped QK^T, sigma'd V: R17) + cos/sin staged into LDS
//      by global_load_lds like K/V (R14 mechanism) -> loop body has NO VMEM reads:
//      ds_read + MFMA + VALU only. R17/R18's regression was in-order vmcnt draining
//      staging at the mid-iter cos/sin load; that load no longer exists.

#define S_LEN 2048
#define NHEADS 16

typedef __attribute__((ext_vector_type(8))) short short8;
typedef __attribute__((ext_vector_type(4))) float floatx4;
typedef __attribute__((ext_vector_type(2))) float float2v;

__device__ inline unsigned short f2bf(float f) {
    union { float f; unsigned int i; } v; v.f = f;
    unsigned int u = v.i;
    return (unsigned short)((u + 0x7fffu + ((u >> 16) & 1u)) >> 16);
}
// pack two f32 -> packed bf16 u32 (truncation), low short = lo
__device__ inline unsigned int pack2_bf16(float hi, float lo) {
    union { float f; unsigned int u; } a, b; a.f = hi; b.f = lo;
    return __builtin_amdgcn_perm(a.u, b.u, 0x07060302u);
}
__device__ inline void async_copy16(const unsigned short* src, unsigned short* dst_lds) {
    __builtin_amdgcn_global_load_lds(
        (const __attribute__((address_space(1))) unsigned int*)(src),
        (__attribute__((address_space(3))) unsigned int*)(dst_lds), 16, 0, 0);
}
__device__ inline void async_copy4(const float* src, float* dst_lds) {
    __builtin_amdgcn_global_load_lds(
        (const __attribute__((address_space(1))) unsigned int*)(src),
        (__attribute__((address_space(3))) unsigned int*)(dst_lds), 4, 0, 0);
}

// ---------------- prep: phase+cvt (blocks 0..4095) | weight transpose (4096..5119)
__global__ __launch_bounds__(256) void prep_kernel(
    const float* __restrict__ x, const float* __restrict__ Wp,
    const float* __restrict__ bp,
    const float* __restrict__ w0, const float* __restrict__ w1,
    const float* __restrict__ w2, const float* __restrict__ w3,
    unsigned short* __restrict__ d0, unsigned short* __restrict__ d1,
    unsigned short* __restrict__ d2, unsigned short* __restrict__ d3,
    float* __restrict__ cosP, float* __restrict__ sinP,
    unsigned short* __restrict__ xb) {
    __shared__ __align__(16) unsigned short shmem[64 * 72];   // 9216 B union
    int t = threadIdx.x;
    if (blockIdx.x < 4096) {
        float* fb = reinterpret_cast<float*>(shmem);
        float* xs = fb;                                        // [1024] f32 x row
        float4* red4 = reinterpret_cast<float4*>(fb + 1024);   // [256] float4 partials
        int bid = blockIdx.x;
        int b = bid >> 11, s = bid & 2047;
        const float* xr = x + (size_t)bid * 1024;
        float4 xv = *reinterpret_cast<const float4*>(&xr[t * 4]);
        {
            uint2 o;
            o.x = (unsigned int)f2bf(xv.x) | ((unsigned int)f2bf(xv.y) << 16);
            o.y = (unsigned int)f2bf(xv.z) | ((unsigned int)f2bf(xv.w) << 16);
            *reinterpret_cast<uint2*>(&xb[(size_t)bid * 1024 + t * 4]) = o;
        }
        *reinterpret_cast<float4*>(&xs[t * 4]) = xv;
        __syncthreads();
        // coalesced GEMV: thread t owns h-block (t&3)*4, k rows i*64 + (t>>2)
        float f0 = 0.f, f1 = 0.f, f2 = 0.f, f3 = 0.f;
        int krow = t >> 2;
        const float4* wp4 = reinterpret_cast<const float4*>(Wp);
#pragma unroll
        for (int i = 0; i < 16; i++) {
            float4 wv = wp4[i * 256 + t];          // lane stride 16B: coalesced
            float xk = xs[i * 64 + krow];          // 4-lane broadcast, conflict-free
            f0 += xk * wv.x; f1 += xk * wv.y; f2 += xk * wv.z; f3 += xk * wv.w;
        }
        red4[t] = make_float4(f0, f1, f2, f3);
        __syncthreads();
        if (t < 16) {
            int b2 = t >> 2, comp = t & 3;
            const float* rf = fb + 1024;           // scalar view of red4
            float sum = bp[t];
#pragma unroll
            for (int j = 0; j < 64; j++) sum += rf[(4 * j + b2) * 4 + comp];
            float sv, cv;
            __sincosf(sum, &sv, &cv);
            size_t o = ((size_t)b * NHEADS + t) * S_LEN + s;
            cosP[o] = cv; sinP[o] = sv;
        }
    } else {
        unsigned short (*tile)[72] = reinterpret_cast<unsigned short (*)[72]>(shmem);
        int bid = blockIdx.x - 4096;
        int mat = bid >> 8;
        int tl  = bid & 255;
        int tr = tl >> 4, tc = tl & 15;
        const float* src    = (mat == 0) ? w0 : (mat == 1) ? w1 : (mat == 2) ? w2 : w3;
        unsigned short* dst = (mat == 0) ? d0 : (mat == 1) ? d1 : (mat == 2) ? d2 : d3;
        int col = t & 63, rbase = (t >> 6) * 16;
#pragma unroll
        for (int i = 0; i < 16; i++) {
            int row = rbase + i;
            tile[row][col] = f2bf(src[(size_t)(tr * 64 + row) * 1024 + tc * 64 + col]);
        }
        __syncthreads();
#pragma unroll
        for (int i = 0; i < 16; i++) {
            int row = rbase + i;
            dst[(size_t)(tc * 64 + row) * 1024 + tr * 64 + col] = tile[col][row];
        }
    }
}

// ---------------- GEMM (m97 recipe, baseline BK=32) ------------------------------
// mode 0: row-major fp32 out (+bias) -> of
// mode 1: N=3072 QKV: Q scaled 0.125*log2e -> (B,H,S,dk); K -> (B,H,S,dk);
//         V -> (B,H,dk,S) transposed, sigma-interleaved per 64-token chunk:
//         token j at short u = (jt>>1)*32 + ((j&15)>>2)*8 + (jt&1)*4 + (j&3), jt=j>>4.
template <int MT>
__global__ __launch_bounds__(256) void gemm_bt(
    const unsigned short* __restrict__ A, const unsigned short* __restrict__ BT,
    int N, int mode,
    const float* __restrict__ b0, const float* __restrict__ b1,
    const float* __restrict__ b2,
    unsigned short* __restrict__ o0, unsigned short* __restrict__ o1,
    unsigned short* __restrict__ o2, float* __restrict__ of) {
    __shared__ __align__(16) unsigned short As[MT * 32];
    __shared__ __align__(16) unsigned short Bs[128 * 32];
    const int K = 1024;
    const int MI = MT / 32;
    int t = threadIdx.x;
    int mBase = blockIdx.x * MT;
    int nBase = blockIdx.y * 128;
    int w = t >> 6, lane = t & 63, l15 = lane & 15, quad = lane >> 4;
    int wm = (w & 1) * (MT / 2), wn = (w >> 1) * 64;
    floatx4 acc[MI][4];
#pragma unroll
    for (int i = 0; i < MI; i++)
#pragma unroll
        for (int j = 0; j < 4; j++) acc[i][j] = (floatx4){0.f, 0.f, 0.f, 0.f};

    int arow = t >> 2, aseg = (t & 3) * 8;
    for (int k0 = 0; k0 < K; k0 += 32) {
        __syncthreads();
#pragma unroll
        for (int i = 0; i < MT / 64; i++)
            async_copy16(&A[(size_t)(mBase + i * 64 + arow) * K + k0 + aseg],
                         &As[(i * 64 + arow) * 32 + aseg]);
#pragma unroll
        for (int i = 0; i < 2; i++)
            async_copy16(&BT[(size_t)(nBase + i * 64 + arow) * K + k0 + aseg],
                         &Bs[(i * 64 + arow) * 32 + aseg]);
        __syncthreads();
        short8 af[MI], bfr[4];
#pragma unroll
        for (int mi = 0; mi < MI; mi++)
            af[mi] = *reinterpret_cast<const short8*>(&As[(wm + mi * 16 + l15) * 32 + quad * 8]);
#pragma unroll
        for (int ni = 0; ni < 4; ni++)
            bfr[ni] = *reinterpret_cast<const short8*>(&Bs[(wn + ni * 16 + l15) * 32 + quad * 8]);
#pragma unroll
        for (int mi = 0; mi < MI; mi++)
#pragma unroll
            for (int ni = 0; ni < 4; ni++)
                acc[mi][ni] = __builtin_amdgcn_mfma_f32_16x16x32_bf16(af[mi], bfr[ni], acc[mi][ni], 0, 0, 0);
    }

#pragma unroll
    for (int mi = 0; mi < MI; mi++) {
        int rowB = mBase + wm + mi * 16 + quad * 4;
#pragma unroll
        for (int ni = 0; ni < 4; ni++) {
            int col = nBase + wn + ni * 16 + l15;
            if (mode == 0) {
                float bias = b0[col];
#pragma unroll
                for (int r = 0; r < 4; r++) {
                    of[(size_t)(rowB + r) * N + col] = acc[mi][ni][r] + bias;
                }
            } else {
                int mat = col >> 10, nn = col & 1023;
                int h = nn >> 6, d = nn & 63;
                int b = rowB >> 11, sidx = rowB & 2047;
                if (mat == 2) {
                    float bv = b2[nn];
                    int jj = sidx & 63;                 // multiple of 4
                    size_t rowOff = ((size_t)((b * NHEADS + h) * 64 + d)) * S_LEN +
                                    (sidx & ~63);
#pragma unroll
                    for (int r = 0; r < 4; r++) {
                        int j2 = jj + r;
                        int jt = j2 >> 4;
                        int u = (jt >> 1) * 32 + ((j2 & 15) >> 2) * 8 + (jt & 1) * 4 + (j2 & 3);
                        o2[rowOff + u] = f2bf(acc[mi][ni][r] + bv);
                    }
                } else {
                    const float* bias  = (mat == 0) ? b0 : b1;
                    unsigned short* op = (mat == 0) ? o0 : o1;
                    float bv = bias[nn];
                    float scl = (mat == 0) ? 0.18033688f : 1.0f;  // dk^-0.5 * log2e
#pragma unroll
                    for (int r = 0; r < 4; r++) {
                        float cv = (acc[mi][ni][r] + bv) * scl;
                        op[(((size_t)b * NHEADS + h) * S_LEN + (sidx + r)) * 64 + d] = f2bf(cv);
                    }
                }
            }
        }
    }
}

// ---------------- flash attention, oscillatory coherence ------------------------
// grid = 256 blocks (1 per CU), 1024 thr (16 waves x 16 Q-rows = 256 Q-rows/block).
// XCD-swizzled. Register-P (swapped QK^T, sigma'd V) + cos/sin staged to LDS by
// global_load_lds -> loop body: ds_read + MFMA + VALU only (no VMEM reads).
__global__ __launch_bounds__(1024) void attn_kernel(
    const unsigned short* __restrict__ Qg, const unsigned short* __restrict__ Kg,
    const unsigned short* __restrict__ VTg,
    const float* __restrict__ cosP, const float* __restrict__ sinP,
    const float* __restrict__ alpha, unsigned short* __restrict__ ctx) {
    __shared__ __align__(16) unsigned short KsB[2][64 * 64];
    __shared__ __align__(16) unsigned short VtB[2][64 * 64];
    __shared__ __align__(16) float csB[2][128];      // cos 0..63, sin 64..127

    int x = blockIdx.x;                     // 0..255
    int bh = (x & 7) * 4 + (x >> 6);        // XCD (x%8) owns 4 consecutive bh groups
    int qt = (x >> 3) & 7;                  // 8 Q-tiles of 256 rows per bh
    int t = threadIdx.x, w = t >> 6, lane = t & 63, l15 = lane & 15, quad = lane >> 4;
    int m0 = qt * 256 + w * 16;
    size_t base = (size_t)bh * (S_LEN * 64);
    size_t phBase = (size_t)bh * S_LEN;
    const float L2E = 1.44269504f;

    // staging geometry: threads 0..511 own K bytes [16t,16t+16), 512..1023 own V
    int th = t & 511;
    int sj = th >> 3, sg = th & 7;
    int srot = ((sg - (sj & 7)) & 7) * 8;   // shorts: un-rotated global column
    bool stK = (t < 512);

    // Q frags; Q pre-scaled by 0.125*L2E. Used as B-operand (col = Q-row = l15).
    short8 qf[2];
#pragma unroll
    for (int c = 0; c < 2; c++)
        qf[c] = *reinterpret_cast<const short8*>(
            &Qg[base + (size_t)(m0 + l15) * 64 + c * 32 + quad * 8]);

    float alph = alpha[bh & 15] * L2E;
    // per-lane coherence coefficients for this thread's Q-row (m0 + l15)
    float ci = alph * cosP[phBase + m0 + l15];
    float si = alph * sinP[phBase + m0 + l15];
    float2v ci2 = (float2v){ci, ci}, si2 = (float2v){si, si};

    {   // stage kt=0 -> buf 0 (K, V, cos/sin)
        if (stK) async_copy16(&Kg[base + (size_t)sj * 64 + srot], &KsB[0][th * 8]);
        else     async_copy16(&VTg[base + (size_t)sj * S_LEN + srot], &VtB[0][th * 8]);
        if (w == 4)      async_copy4(&cosP[phBase + lane], &csB[0][lane]);
        else if (w == 5) async_copy4(&sinP[phBase + lane], &csB[0][64 + lane]);
    }

    floatx4 oacc[4], lacc;
#pragma unroll
    for (int tt = 0; tt < 4; tt++) oacc[tt] = (floatx4){0.f, 0.f, 0.f, 0.f};
    lacc = (floatx4){0.f, 0.f, 0.f, 0.f};
    const short8 ones8 = {(short)0x3F80, (short)0x3F80, (short)0x3F80, (short)0x3F80,
                          (short)0x3F80, (short)0x3F80, (short)0x3F80, (short)0x3F80};

    // frag-read rotation
    int rot = l15 & 7;
    int cb0 = 16 * ((quad + rot) & 7);        // bytes, k-chunk c=0
    int cb1 = 16 * ((quad + 4 + rot) & 7);    // bytes, k-chunk c=1

    for (int kt = 0; kt < 32; kt++) {
        int p = kt & 1;
        __syncthreads();   // staging for kt complete; buf p^1 free
        if (kt < 31) {
            int kn = kt + 1, pn = p ^ 1;
            if (stK) async_copy16(&Kg[base + (size_t)(kn * 64 + sj) * 64 + srot], &KsB[pn][th * 8]);
            else     async_copy16(&VTg[base + (size_t)sj * S_LEN + kn * 64 + srot], &VtB[pn][th * 8]);
            if (w == 4)      async_copy4(&cosP[phBase + kn * 64 + lane], &csB[pn][lane]);
            else if (w == 5) async_copy4(&sinP[phBase + kn * 64 + lane], &csB[pn][64 + lane]);
        }

        // QK^T swapped: st[jt][r] = score[K-tok kt*64+jt*16+quad*4+r][Q-row m0+l15]
        floatx4 st[4];
#pragma unroll
        for (int jt = 0; jt < 4; jt++) {
            const char* kr = (const char*)&KsB[p][(jt * 16 + l15) * 64];
            short8 kf0 = *reinterpret_cast<const short8*>(kr + cb0);
            short8 kf1 = *reinterpret_cast<const short8*>(kr + cb1);
            floatx4 s = (floatx4){0.f, 0.f, 0.f, 0.f};
            s = __builtin_amdgcn_mfma_f32_16x16x32_bf16(kf0, qf[0], s, 0, 0, 0);
            s = __builtin_amdgcn_mfma_f32_16x16x32_bf16(kf1, qf[1], s, 0, 0, 0);
            st[jt] = s;
        }

        // P = exp2(st + ci*cos(phi_j) + si*sin(phi_j)), packed in-register.
        // cos/sin from LDS: quad-uniform float4 reads (broadcast, conflict-free).
        union PW { unsigned int u[4]; short8 s8; };
        PW P0, P1;
#pragma unroll
        for (int jt = 0; jt < 4; jt++) {
            float4 cj4 = *reinterpret_cast<const float4*>(&csB[p][jt * 16 + quad * 4]);
            float4 sj4 = *reinterpret_cast<const float4*>(&csB[p][64 + jt * 16 + quad * 4]);
            float2v st01 = (float2v){st[jt][0], st[jt][1]};
            float2v st23 = (float2v){st[jt][2], st[jt][3]};
            float2v c01 = (float2v){cj4.x, cj4.y}, c23 = (float2v){cj4.z, cj4.w};
            float2v s01 = (float2v){sj4.x, sj4.y}, s23 = (float2v){sj4.z, sj4.w};
            float2v a01 = si2 * s01 + (ci2 * c01 + st01);
            float2v a23 = si2 * s23 + (ci2 * c23 + st23);
            unsigned int wA = pack2_bf16(__builtin_amdgcn_exp2f(a01.y),
                                         __builtin_amdgcn_exp2f(a01.x));
            unsigned int wB = pack2_bf16(__builtin_amdgcn_exp2f(a23.y),
                                         __builtin_amdgcn_exp2f(a23.x));
            if (jt == 0)      { P0.u[0] = wA; P0.u[1] = wB; }
            else if (jt == 1) { P0.u[2] = wA; P0.u[3] = wB; }
            else if (jt == 2) { P1.u[0] = wA; P1.u[1] = wB; }
            else              { P1.u[2] = wA; P1.u[3] = wB; }
        }

        // O += P @ V; l += P @ ones   (V stored with matching sigma)
#pragma unroll
        for (int c = 0; c < 2; c++) {
            short8 pf = c ? P1.s8 : P0.s8;
            int cb = c ? cb1 : cb0;
#pragma unroll
            for (int tt = 0; tt < 4; tt++) {
                const char* vr = (const char*)&VtB[p][(tt * 16 + l15) * 64];
                short8 vf = *reinterpret_cast<const short8*>(vr + cb);
                oacc[tt] = __builtin_amdgcn_mfma_f32_16x16x32_bf16(pf, vf, oacc[tt], 0, 0, 0);
            }
            lacc = __builtin_amdgcn_mfma_f32_16x16x32_bf16(pf, ones8, lacc, 0, 0, 0);
        }
    }

    // epilogue: normalize rows by l and write ctx[b][s][h*64+d]
    int b = bh >> 4, h = bh & 15;
    float inv[4];
#pragma unroll
    for (int r = 0; r < 4; r++) inv[r] = 1.0f / lacc[r];
#pragma unroll
    for (int tt = 0; tt < 4; tt++)
#pragma unroll
        for (int r = 0; r < 4; r++) {
            int srow = m0 + quad * 4 + r;
            ctx[((size_t)(b * S_LEN + srow)) * 1024 + h * 64 + tt * 16 + l15] =
                f2bf(oacc[tt][r] * inv[r]);
        }
}

extern "C" void kernel_launch(void* const* d_in, const int* in_sizes, int n_in,
                              void* d_out, int out_size, void* d_ws, size_t ws_size,
                              hipStream_t stream) {
    const float* x     = (const float*)d_in[0];
    const float* Wq    = (const float*)d_in[1];
    const float* bq    = (const float*)d_in[2];
    const float* Wk    = (const float*)d_in[3];
    const float* bk    = (const float*)d_in[4];
    const float* Wv    = (const float*)d_in[5];
    const float* bv    = (const float*)d_in[6];
    const float* Wo    = (const float*)d_in[7];
    const float* bo    = (const float*)d_in[8];
    const float* Wp    = (const float*)d_in[9];
    const float* bp    = (const float*)d_in[10];
    const float* alpha = (const float*)d_in[11];
    float* out = (float*)d_out;

    const size_t MB = 1048576;
    char* ws = (char*)d_ws;
    unsigned short* WT   = (unsigned short*)(ws);             // 3072x1024 bf16
    unsigned short* WoT  = (unsigned short*)(ws + 6 * MB);    // 1024x1024 bf16
    unsigned short* xb   = (unsigned short*)(ws + 8 * MB);    // (B,S,D) bf16
    unsigned short* ctx  = (unsigned short*)(ws + 8 * MB);    // aliases xb
    unsigned short* Qw   = (unsigned short*)(ws + 16 * MB);   // (B,H,S,dk), pre-scaled
    unsigned short* Kw   = (unsigned short*)(ws + 24 * MB);   // (B,H,S,dk)
    unsigned short* VTg  = (unsigned short*)(ws + 32 * MB);   // (B,H,dk,S) sigma-interleaved
    float* cosP          = (float*)(ws + 40 * MB);
    float* sinP          = (float*)(ws + 40 * MB + 262144);

    prep_kernel<<<dim3(5120), dim3(256), 0, stream>>>(
        x, Wp, bp, Wq, Wk, Wv, Wo,
        WT, WT + 1048576, WT + 2097152, WoT, cosP, sinP, xb);
    gemm_bt<128><<<dim3(32, 24), dim3(256), 0, stream>>>(
        xb, WT, 3072, 1, bq, bk, bv, Qw, Kw, VTg, (float*)nullptr);
    attn_kernel<<<dim3(256), dim3(1024), 0, stream>>>(
        Qw, Kw, VTg, cosP, sinP, alpha, ctx);
    gemm_bt<64><<<dim3(64, 8), dim3(256), 0, stream>>>(
        ctx, WoT, 1024, 0, bo, bo, bo,
        (unsigned short*)nullptr, (unsigned short*)nullptr,
        (unsigned short*)nullptr, out);
}

// Round 14
// 222.175 us; speedup vs baseline: 1.0901x; 1.0000x over previous
//
#include <hip/hip_runtime.h>
#include <math.h>

// OscillatoryAttention: B=2,S=2048,D=1024,H=16,dk=64. FP32 in/out, bf16 MFMA inside.
// R20: attn = R19 register-P + HALVED BARRIER COUNT. 4-deep staging buffers; barrier
//      only at even kt (drains copies issued at kt-2 for tiles kt,kt+1; tiles kt+2,kt+3
//      issued post-barrier overwrite buffers last read at kt-2/kt-1 -> safe). 32->16
//      barriers tests the wave-resync hypothesis (the only invariant left across the
//      four 57.5-59.5us structures). + s_setprio(1) around MFMA clusters (T5).

#define S_LEN 2048
#define NHEADS 16

typedef __attribute__((ext_vector_type(8))) short short8;
typedef __attribute__((ext_vector_type(4))) float floatx4;
typedef __attribute__((ext_vector_type(2))) float float2v;

__device__ inline unsigned short f2bf(float f) {
    union { float f; unsigned int i; } v; v.f = f;
    unsigned int u = v.i;
    return (unsigned short)((u + 0x7fffu + ((u >> 16) & 1u)) >> 16);
}
// pack two f32 -> packed bf16 u32 (truncation), low short = lo
__device__ inline unsigned int pack2_bf16(float hi, float lo) {
    union { float f; unsigned int u; } a, b; a.f = hi; b.f = lo;
    return __builtin_amdgcn_perm(a.u, b.u, 0x07060302u);
}
__device__ inline void async_copy16(const unsigned short* src, unsigned short* dst_lds) {
    __builtin_amdgcn_global_load_lds(
        (const __attribute__((address_space(1))) unsigned int*)(src),
        (__attribute__((address_space(3))) unsigned int*)(dst_lds), 16, 0, 0);
}
__device__ inline void async_copy4(const float* src, float* dst_lds) {
    __builtin_amdgcn_global_load_lds(
        (const __attribute__((address_space(1))) unsigned int*)(src),
        (__attribute__((address_space(3))) unsigned int*)(dst_lds), 4, 0, 0);
}

// ---------------- prep: phase+cvt (blocks 0..4095) | weight transpose (4096..5119)
__global__ __launch_bounds__(256) void prep_kernel(
    const float* __restrict__ x, const float* __restrict__ Wp,
    const float* __restrict__ bp,
    const float* __restrict__ w0, const float* __restrict__ w1,
    const float* __restrict__ w2, const float* __restrict__ w3,
    unsigned short* __restrict__ d0, unsigned short* __restrict__ d1,
    unsigned short* __restrict__ d2, unsigned short* __restrict__ d3,
    float* __restrict__ cosP, float* __restrict__ sinP,
    unsigned short* __restrict__ xb) {
    __shared__ __align__(16) unsigned short shmem[64 * 72];   // 9216 B union
    int t = threadIdx.x;
    if (blockIdx.x < 4096) {
        float* fb = reinterpret_cast<float*>(shmem);
        float* xs = fb;                                        // [1024] f32 x row
        float4* red4 = reinterpret_cast<float4*>(fb + 1024);   // [256] float4 partials
        int bid = blockIdx.x;
        int b = bid >> 11, s = bid & 2047;
        const float* xr = x + (size_t)bid * 1024;
        float4 xv = *reinterpret_cast<const float4*>(&xr[t * 4]);
        {
            uint2 o;
            o.x = (unsigned int)f2bf(xv.x) | ((unsigned int)f2bf(xv.y) << 16);
            o.y = (unsigned int)f2bf(xv.z) | ((unsigned int)f2bf(xv.w) << 16);
            *reinterpret_cast<uint2*>(&xb[(size_t)bid * 1024 + t * 4]) = o;
        }
        *reinterpret_cast<float4*>(&xs[t * 4]) = xv;
        __syncthreads();
        // coalesced GEMV: thread t owns h-block (t&3)*4, k rows i*64 + (t>>2)
        float f0 = 0.f, f1 = 0.f, f2 = 0.f, f3 = 0.f;
        int krow = t >> 2;
        const float4* wp4 = reinterpret_cast<const float4*>(Wp);
#pragma unroll
        for (int i = 0; i < 16; i++) {
            float4 wv = wp4[i * 256 + t];          // lane stride 16B: coalesced
            float xk = xs[i * 64 + krow];          // 4-lane broadcast, conflict-free
            f0 += xk * wv.x; f1 += xk * wv.y; f2 += xk * wv.z; f3 += xk * wv.w;
        }
        red4[t] = make_float4(f0, f1, f2, f3);
        __syncthreads();
        if (t < 16) {
            int b2 = t >> 2, comp = t & 3;
            const float* rf = fb + 1024;           // scalar view of red4
            float sum = bp[t];
#pragma unroll
            for (int j = 0; j < 64; j++) sum += rf[(4 * j + b2) * 4 + comp];
            float sv, cv;
            __sincosf(sum, &sv, &cv);
            size_t o = ((size_t)b * NHEADS + t) * S_LEN + s;
            cosP[o] = cv; sinP[o] = sv;
        }
    } else {
        unsigned short (*tile)[72] = reinterpret_cast<unsigned short (*)[72]>(shmem);
        int bid = blockIdx.x - 4096;
        int mat = bid >> 8;
        int tl  = bid & 255;
        int tr = tl >> 4, tc = tl & 15;
        const float* src    = (mat == 0) ? w0 : (mat == 1) ? w1 : (mat == 2) ? w2 : w3;
        unsigned short* dst = (mat == 0) ? d0 : (mat == 1) ? d1 : (mat == 2) ? d2 : d3;
        int col = t & 63, rbase = (t >> 6) * 16;
#pragma unroll
        for (int i = 0; i < 16; i++) {
            int row = rbase + i;
            tile[row][col] = f2bf(src[(size_t)(tr * 64 + row) * 1024 + tc * 64 + col]);
        }
        __syncthreads();
#pragma unroll
        for (int i = 0; i < 16; i++) {
            int row = rbase + i;
            dst[(size_t)(tc * 64 + row) * 1024 + tr * 64 + col] = tile[col][row];
        }
    }
}

// ---------------- GEMM (m97 recipe, baseline BK=32) ------------------------------
// mode 0: row-major fp32 out (+bias) -> of
// mode 1: N=3072 QKV: Q scaled 0.125*log2e -> (B,H,S,dk); K -> (B,H,S,dk);
//         V -> (B,H,dk,S) transposed, sigma-interleaved per 64-token chunk:
//         token j at short u = (jt>>1)*32 + ((j&15)>>2)*8 + (jt&1)*4 + (j&3), jt=j>>4.
template <int MT>
__global__ __launch_bounds__(256) void gemm_bt(
    const unsigned short* __restrict__ A, const unsigned short* __restrict__ BT,
    int N, int mode,
    const float* __restrict__ b0, const float* __restrict__ b1,
    const float* __restrict__ b2,
    unsigned short* __restrict__ o0, unsigned short* __restrict__ o1,
    unsigned short* __restrict__ o2, float* __restrict__ of) {
    __shared__ __align__(16) unsigned short As[MT * 32];
    __shared__ __align__(16) unsigned short Bs[128 * 32];
    const int K = 1024;
    const int MI = MT / 32;
    int t = threadIdx.x;
    int mBase = blockIdx.x * MT;
    int nBase = blockIdx.y * 128;
    int w = t >> 6, lane = t & 63, l15 = lane & 15, quad = lane >> 4;
    int wm = (w & 1) * (MT / 2), wn = (w >> 1) * 64;
    floatx4 acc[MI][4];
#pragma unroll
    for (int i = 0; i < MI; i++)
#pragma unroll
        for (int j = 0; j < 4; j++) acc[i][j] = (floatx4){0.f, 0.f, 0.f, 0.f};

    int arow = t >> 2, aseg = (t & 3) * 8;
    for (int k0 = 0; k0 < K; k0 += 32) {
        __syncthreads();
#pragma unroll
        for (int i = 0; i < MT / 64; i++)
            async_copy16(&A[(size_t)(mBase + i * 64 + arow) * K + k0 + aseg],
                         &As[(i * 64 + arow) * 32 + aseg]);
#pragma unroll
        for (int i = 0; i < 2; i++)
            async_copy16(&BT[(size_t)(nBase + i * 64 + arow) * K + k0 + aseg],
                         &Bs[(i * 64 + arow) * 32 + aseg]);
        __syncthreads();
        short8 af[MI], bfr[4];
#pragma unroll
        for (int mi = 0; mi < MI; mi++)
            af[mi] = *reinterpret_cast<const short8*>(&As[(wm + mi * 16 + l15) * 32 + quad * 8]);
#pragma unroll
        for (int ni = 0; ni < 4; ni++)
            bfr[ni] = *reinterpret_cast<const short8*>(&Bs[(wn + ni * 16 + l15) * 32 + quad * 8]);
#pragma unroll
        for (int mi = 0; mi < MI; mi++)
#pragma unroll
            for (int ni = 0; ni < 4; ni++)
                acc[mi][ni] = __builtin_amdgcn_mfma_f32_16x16x32_bf16(af[mi], bfr[ni], acc[mi][ni], 0, 0, 0);
    }

#pragma unroll
    for (int mi = 0; mi < MI; mi++) {
        int rowB = mBase + wm + mi * 16 + quad * 4;
#pragma unroll
        for (int ni = 0; ni < 4; ni++) {
            int col = nBase + wn + ni * 16 + l15;
            if (mode == 0) {
                float bias = b0[col];
#pragma unroll
                for (int r = 0; r < 4; r++) {
                    of[(size_t)(rowB + r) * N + col] = acc[mi][ni][r] + bias;
                }
            } else {
                int mat = col >> 10, nn = col & 1023;
                int h = nn >> 6, d = nn & 63;
                int b = rowB >> 11, sidx = rowB & 2047;
                if (mat == 2) {
                    float bv = b2[nn];
                    int jj = sidx & 63;                 // multiple of 4
                    size_t rowOff = ((size_t)((b * NHEADS + h) * 64 + d)) * S_LEN +
                                    (sidx & ~63);
#pragma unroll
                    for (int r = 0; r < 4; r++) {
                        int j2 = jj + r;
                        int jt = j2 >> 4;
                        int u = (jt >> 1) * 32 + ((j2 & 15) >> 2) * 8 + (jt & 1) * 4 + (j2 & 3);
                        o2[rowOff + u] = f2bf(acc[mi][ni][r] + bv);
                    }
                } else {
                    const float* bias  = (mat == 0) ? b0 : b1;
                    unsigned short* op = (mat == 0) ? o0 : o1;
                    float bv = bias[nn];
                    float scl = (mat == 0) ? 0.18033688f : 1.0f;  // dk^-0.5 * log2e
#pragma unroll
                    for (int r = 0; r < 4; r++) {
                        float cv = (acc[mi][ni][r] + bv) * scl;
                        op[(((size_t)b * NHEADS + h) * S_LEN + (sidx + r)) * 64 + d] = f2bf(cv);
                    }
                }
            }
        }
    }
}

// ---------------- flash attention, oscillatory coherence ------------------------
// grid = 256 blocks (1 per CU), 1024 thr (16 waves x 16 Q-rows = 256 Q-rows/block).
// XCD-swizzled. Register-P (swapped QK^T, sigma'd V) + cos/sin staged to LDS.
// R20: 4-deep buffers, barrier only at even kt (16 barriers instead of 32);
// staging for kt+2 and kt+3 issued right after the even-kt barrier.
__global__ __launch_bounds__(1024) void attn_kernel(
    const unsigned short* __restrict__ Qg, const unsigned short* __restrict__ Kg,
    const unsigned short* __restrict__ VTg,
    const float* __restrict__ cosP, const float* __restrict__ sinP,
    const float* __restrict__ alpha, unsigned short* __restrict__ ctx) {
    __shared__ __align__(16) unsigned short KsB[4][64 * 64];   // 32 KB
    __shared__ __align__(16) unsigned short VtB[4][64 * 64];   // 32 KB
    __shared__ __align__(16) float csB[4][128];                // 2 KB

    int x = blockIdx.x;                     // 0..255
    int bh = (x & 7) * 4 + (x >> 6);        // XCD (x%8) owns 4 consecutive bh groups
    int qt = (x >> 3) & 7;                  // 8 Q-tiles of 256 rows per bh
    int t = threadIdx.x, w = t >> 6, lane = t & 63, l15 = lane & 15, quad = lane >> 4;
    int m0 = qt * 256 + w * 16;
    size_t base = (size_t)bh * (S_LEN * 64);
    size_t phBase = (size_t)bh * S_LEN;
    const float L2E = 1.44269504f;

    // staging geometry: threads 0..511 own K bytes [16t,16t+16), 512..1023 own V
    int th = t & 511;
    int sj = th >> 3, sg = th & 7;
    int srot = ((sg - (sj & 7)) & 7) * 8;   // shorts: un-rotated global column
    bool stK = (t < 512);

    // Q frags; Q pre-scaled by 0.125*L2E. Used as B-operand (col = Q-row = l15).
    short8 qf[2];
#pragma unroll
    for (int c = 0; c < 2; c++)
        qf[c] = *reinterpret_cast<const short8*>(
            &Qg[base + (size_t)(m0 + l15) * 64 + c * 32 + quad * 8]);

    float alph = alpha[bh & 15] * L2E;
    // per-lane coherence coefficients for this thread's Q-row (m0 + l15)
    float ci = alph * cosP[phBase + m0 + l15];
    float si = alph * sinP[phBase + m0 + l15];
    float2v ci2 = (float2v){ci, ci}, si2 = (float2v){si, si};

    {   // prologue: stage tiles 0 and 1 -> bufs 0,1
#pragma unroll
        for (int t0 = 0; t0 < 2; t0++) {
            if (stK) async_copy16(&Kg[base + (size_t)(t0 * 64 + sj) * 64 + srot], &KsB[t0][th * 8]);
            else     async_copy16(&VTg[base + (size_t)sj * S_LEN + t0 * 64 + srot], &VtB[t0][th * 8]);
            if (w == 4)      async_copy4(&cosP[phBase + t0 * 64 + lane], &csB[t0][lane]);
            else if (w == 5) async_copy4(&sinP[phBase + t0 * 64 + lane], &csB[t0][64 + lane]);
        }
    }

    floatx4 oacc[4], lacc;
#pragma unroll
    for (int tt = 0; tt < 4; tt++) oacc[tt] = (floatx4){0.f, 0.f, 0.f, 0.f};
    lacc = (floatx4){0.f, 0.f, 0.f, 0.f};
    const short8 ones8 = {(short)0x3F80, (short)0x3F80, (short)0x3F80, (short)0x3F80,
                          (short)0x3F80, (short)0x3F80, (short)0x3F80, (short)0x3F80};

    // frag-read rotation
    int rot = l15 & 7;
    int cb0 = 16 * ((quad + rot) & 7);        // bytes, k-chunk c=0
    int cb1 = 16 * ((quad + 4 + rot) & 7);    // bytes, k-chunk c=1

    for (int kt = 0; kt < 32; kt++) {
        int p = kt & 3;
        if ((kt & 1) == 0) {
            __syncthreads();   // drains copies issued at kt-2 (tiles kt, kt+1);
                               // all waves done with iters <= kt-1
#pragma unroll
            for (int d = 2; d <= 3; d++) {
                int kn = kt + d;
                if (kn < 32) {
                    int pn = kn & 3;
                    if (stK) async_copy16(&Kg[base + (size_t)(kn * 64 + sj) * 64 + srot], &KsB[pn][th * 8]);
                    else     async_copy16(&VTg[base + (size_t)sj * S_LEN + kn * 64 + srot], &VtB[pn][th * 8]);
                    if (w == 4)      async_copy4(&cosP[phBase + kn * 64 + lane], &csB[pn][lane]);
                    else if (w == 5) async_copy4(&sinP[phBase + kn * 64 + lane], &csB[pn][64 + lane]);
                }
            }
        }

        // QK^T swapped: st[jt][r] = score[K-tok kt*64+jt*16+quad*4+r][Q-row m0+l15]
        floatx4 st[4];
        __builtin_amdgcn_s_setprio(1);
#pragma unroll
        for (int jt = 0; jt < 4; jt++) {
            const char* kr = (const char*)&KsB[p][(jt * 16 + l15) * 64];
            short8 kf0 = *reinterpret_cast<const short8*>(kr + cb0);
            short8 kf1 = *reinterpret_cast<const short8*>(kr + cb1);
            floatx4 s = (floatx4){0.f, 0.f, 0.f, 0.f};
            s = __builtin_amdgcn_mfma_f32_16x16x32_bf16(kf0, qf[0], s, 0, 0, 0);
            s = __builtin_amdgcn_mfma_f32_16x16x32_bf16(kf1, qf[1], s, 0, 0, 0);
            st[jt] = s;
        }
        __builtin_amdgcn_s_setprio(0);

        // P = exp2(st + ci*cos(phi_j) + si*sin(phi_j)), packed in-register.
        // cos/sin from LDS: quad-uniform float4 reads (broadcast, conflict-free).
        union PW { unsigned int u[4]; short8 s8; };
        PW P0, P1;
#pragma unroll
        for (int jt = 0; jt < 4; jt++) {
            float4 cj4 = *reinterpret_cast<const float4*>(&csB[p][jt * 16 + quad * 4]);
            float4 sj4 = *reinterpret_cast<const float4*>(&csB[p][64 + jt * 16 + quad * 4]);
            float2v st01 = (float2v){st[jt][0], st[jt][1]};
            float2v st23 = (float2v){st[jt][2], st[jt][3]};
            float2v c01 = (float2v){cj4.x, cj4.y}, c23 = (float2v){cj4.z, cj4.w};
            float2v s01 = (float2v){sj4.x, sj4.y}, s23 = (float2v){sj4.z, sj4.w};
            float2v a01 = si2 * s01 + (ci2 * c01 + st01);
            float2v a23 = si2 * s23 + (ci2 * c23 + st23);
            unsigned int wA = pack2_bf16(__builtin_amdgcn_exp2f(a01.y),
                                         __builtin_amdgcn_exp2f(a01.x));
            unsigned int wB = pack2_bf16(__builtin_amdgcn_exp2f(a23.y),
                                         __builtin_amdgcn_exp2f(a23.x));
            if (jt == 0)      { P0.u[0] = wA; P0.u[1] = wB; }
            else if (jt == 1) { P0.u[2] = wA; P0.u[3] = wB; }
            else if (jt == 2) { P1.u[0] = wA; P1.u[1] = wB; }
            else              { P1.u[2] = wA; P1.u[3] = wB; }
        }

        // O += P @ V; l += P @ ones   (V stored with matching sigma)
        __builtin_amdgcn_s_setprio(1);
#pragma unroll
        for (int c = 0; c < 2; c++) {
            short8 pf = c ? P1.s8 : P0.s8;
            int cb = c ? cb1 : cb0;
#pragma unroll
            for (int tt = 0; tt < 4; tt++) {
                const char* vr = (const char*)&VtB[p][(tt * 16 + l15) * 64];
                short8 vf = *reinterpret_cast<const short8*>(vr + cb);
                oacc[tt] = __builtin_amdgcn_mfma_f32_16x16x32_bf16(pf, vf, oacc[tt], 0, 0, 0);
            }
            lacc = __builtin_amdgcn_mfma_f32_16x16x32_bf16(pf, ones8, lacc, 0, 0, 0);
        }
        __builtin_amdgcn_s_setprio(0);
    }

    // epilogue: normalize rows by l and write ctx[b][s][h*64+d]
    int b = bh >> 4, h = bh & 15;
    float inv[4];
#pragma unroll
    for (int r = 0; r < 4; r++) inv[r] = 1.0f / lacc[r];
#pragma unroll
    for (int tt = 0; tt < 4; tt++)
#pragma unroll
        for (int r = 0; r < 4; r++) {
            int srow = m0 + quad * 4 + r;
            ctx[((size_t)(b * S_LEN + srow)) * 1024 + h * 64 + tt * 16 + l15] =
                f2bf(oacc[tt][r] * inv[r]);
        }
}

extern "C" void kernel_launch(void* const* d_in, const int* in_sizes, int n_in,
                              void* d_out, int out_size, void* d_ws, size_t ws_size,
                              hipStream_t stream) {
    const float* x     = (const float*)d_in[0];
    const float* Wq    = (const float*)d_in[1];
    const float* bq    = (const float*)d_in[2];
    const float* Wk    = (const float*)d_in[3];
    const float* bk    = (const float*)d_in[4];
    const float* Wv    = (const float*)d_in[5];
    const float* bv    = (const float*)d_in[6];
    const float* Wo    = (const float*)d_in[7];
    const float* bo    = (const float*)d_in[8];
    const float* Wp    = (const float*)d_in[9];
    const float* bp    = (const float*)d_in[10];
    const float* alpha = (const float*)d_in[11];
    float* out = (float*)d_out;

    const size_t MB = 1048576;
    char* ws = (char*)d_ws;
    unsigned short* WT   = (unsigned short*)(ws);             // 3072x1024 bf16
    unsigned short* WoT  = (unsigned short*)(ws + 6 * MB);    // 1024x1024 bf16
    unsigned short* xb   = (unsigned short*)(ws + 8 * MB);    // (B,S,D) bf16
    unsigned short* ctx  = (unsigned short*)(ws + 8 * MB);    // aliases xb
    unsigned short* Qw   = (unsigned short*)(ws + 16 * MB);   // (B,H,S,dk), pre-scaled
    unsigned short* Kw   = (unsigned short*)(ws + 24 * MB);   // (B,H,S,dk)
    unsigned short* VTg  = (unsigned short*)(ws + 32 * MB);   // (B,H,dk,S) sigma-interleaved
    float* cosP          = (float*)(ws + 40 * MB);
    float* sinP          = (float*)(ws + 40 * MB + 262144);

    prep_kernel<<<dim3(5120), dim3(256), 0, stream>>>(
        x, Wp, bp, Wq, Wk, Wv, Wo,
        WT, WT + 1048576, WT + 2097152, WoT, cosP, sinP, xb);
    gemm_bt<128><<<dim3(32, 24), dim3(256), 0, stream>>>(
        xb, WT, 3072, 1, bq, bk, bv, Qw, Kw, VTg, (float*)nullptr);
    attn_kernel<<<dim3(256), dim3(1024), 0, stream>>>(
        Qw, Kw, VTg, cosP, sinP, alpha, ctx);
    gemm_bt<64><<<dim3(64, 8), dim3(256), 0, stream>>>(
        ctx, WoT, 1024, 0, bo, bo, bo,
        (unsigned short*)nullptr, (unsigned short*)nullptr,
        (unsigned short*)nullptr, out);
}

// Round 15
// 203.548 us; speedup vs baseline: 1.1898x; 1.0915x over previous
//
#include <hip/hip_runtime.h>
#include <math.h>

// OscillatoryAttention: B=2,S=2048,D=1024,H=16,dk=64. FP32 in/out, bf16 MFMA inside.
// R21: QKV GEMM is the new top dispatch (55.8us, all pipes idle = latency-bound).
//      The m97 2-barrier loop drains JUST-ISSUED staging copies every K-step (2nd
//      barrier's vmcnt(0)). Fix = attn's proven scheme: single barrier/step +
//      double-buffered staging (copies get a full K-step to land) + setprio.
//      Applied to both GEMMs. Attn = R20 (barrier-halved register-P, now <55.7us).

#define S_LEN 2048
#define NHEADS 16

typedef __attribute__((ext_vector_type(8))) short short8;
typedef __attribute__((ext_vector_type(4))) float floatx4;
typedef __attribute__((ext_vector_type(2))) float float2v;

__device__ inline unsigned short f2bf(float f) {
    union { float f; unsigned int i; } v; v.f = f;
    unsigned int u = v.i;
    return (unsigned short)((u + 0x7fffu + ((u >> 16) & 1u)) >> 16);
}
// pack two f32 -> packed bf16 u32 (truncation), low short = lo
__device__ inline unsigned int pack2_bf16(float hi, float lo) {
    union { float f; unsigned int u; } a, b; a.f = hi; b.f = lo;
    return __builtin_amdgcn_perm(a.u, b.u, 0x07060302u);
}
__device__ inline void async_copy16(const unsigned short* src, unsigned short* dst_lds) {
    __builtin_amdgcn_global_load_lds(
        (const __attribute__((address_space(1))) unsigned int*)(src),
        (__attribute__((address_space(3))) unsigned int*)(dst_lds), 16, 0, 0);
}
__device__ inline void async_copy4(const float* src, float* dst_lds) {
    __builtin_amdgcn_global_load_lds(
        (const __attribute__((address_space(1))) unsigned int*)(src),
        (__attribute__((address_space(3))) unsigned int*)(dst_lds), 4, 0, 0);
}

// ---------------- prep: phase+cvt (blocks 0..4095) | weight transpose (4096..5119)
__global__ __launch_bounds__(256) void prep_kernel(
    const float* __restrict__ x, const float* __restrict__ Wp,
    const float* __restrict__ bp,
    const float* __restrict__ w0, const float* __restrict__ w1,
    const float* __restrict__ w2, const float* __restrict__ w3,
    unsigned short* __restrict__ d0, unsigned short* __restrict__ d1,
    unsigned short* __restrict__ d2, unsigned short* __restrict__ d3,
    float* __restrict__ cosP, float* __restrict__ sinP,
    unsigned short* __restrict__ xb) {
    __shared__ __align__(16) unsigned short shmem[64 * 72];   // 9216 B union
    int t = threadIdx.x;
    if (blockIdx.x < 4096) {
        float* fb = reinterpret_cast<float*>(shmem);
        float* xs = fb;                                        // [1024] f32 x row
        float4* red4 = reinterpret_cast<float4*>(fb + 1024);   // [256] float4 partials
        int bid = blockIdx.x;
        int b = bid >> 11, s = bid & 2047;
        const float* xr = x + (size_t)bid * 1024;
        float4 xv = *reinterpret_cast<const float4*>(&xr[t * 4]);
        {
            uint2 o;
            o.x = (unsigned int)f2bf(xv.x) | ((unsigned int)f2bf(xv.y) << 16);
            o.y = (unsigned int)f2bf(xv.z) | ((unsigned int)f2bf(xv.w) << 16);
            *reinterpret_cast<uint2*>(&xb[(size_t)bid * 1024 + t * 4]) = o;
        }
        *reinterpret_cast<float4*>(&xs[t * 4]) = xv;
        __syncthreads();
        // coalesced GEMV: thread t owns h-block (t&3)*4, k rows i*64 + (t>>2)
        float f0 = 0.f, f1 = 0.f, f2 = 0.f, f3 = 0.f;
        int krow = t >> 2;
        const float4* wp4 = reinterpret_cast<const float4*>(Wp);
#pragma unroll
        for (int i = 0; i < 16; i++) {
            float4 wv = wp4[i * 256 + t];          // lane stride 16B: coalesced
            float xk = xs[i * 64 + krow];          // 4-lane broadcast, conflict-free
            f0 += xk * wv.x; f1 += xk * wv.y; f2 += xk * wv.z; f3 += xk * wv.w;
        }
        red4[t] = make_float4(f0, f1, f2, f3);
        __syncthreads();
        if (t < 16) {
            int b2 = t >> 2, comp = t & 3;
            const float* rf = fb + 1024;           // scalar view of red4
            float sum = bp[t];
#pragma unroll
            for (int j = 0; j < 64; j++) sum += rf[(4 * j + b2) * 4 + comp];
            float sv, cv;
            __sincosf(sum, &sv, &cv);
            size_t o = ((size_t)b * NHEADS + t) * S_LEN + s;
            cosP[o] = cv; sinP[o] = sv;
        }
    } else {
        unsigned short (*tile)[72] = reinterpret_cast<unsigned short (*)[72]>(shmem);
        int bid = blockIdx.x - 4096;
        int mat = bid >> 8;
        int tl  = bid & 255;
        int tr = tl >> 4, tc = tl & 15;
        const float* src    = (mat == 0) ? w0 : (mat == 1) ? w1 : (mat == 2) ? w2 : w3;
        unsigned short* dst = (mat == 0) ? d0 : (mat == 1) ? d1 : (mat == 2) ? d2 : d3;
        int col = t & 63, rbase = (t >> 6) * 16;
#pragma unroll
        for (int i = 0; i < 16; i++) {
            int row = rbase + i;
            tile[row][col] = f2bf(src[(size_t)(tr * 64 + row) * 1024 + tc * 64 + col]);
        }
        __syncthreads();
#pragma unroll
        for (int i = 0; i < 16; i++) {
            int row = rbase + i;
            dst[(size_t)(tc * 64 + row) * 1024 + tr * 64 + col] = tile[col][row];
        }
    }
}

// ---------------- GEMM (m97 recipe + single-barrier double-buffered staging) ------
// mode 0: row-major fp32 out (+bias) -> of
// mode 1: N=3072 QKV: Q scaled 0.125*log2e -> (B,H,S,dk); K -> (B,H,S,dk);
//         V -> (B,H,dk,S) transposed, sigma-interleaved per 64-token chunk:
//         token j at short u = (jt>>1)*32 + ((j&15)>>2)*8 + (jt&1)*4 + (j&3), jt=j>>4.
// K-loop: ONE barrier/step. Barrier drains copies issued a full K-step ago
// (~1100cy elapsed >> L2 latency) -> drain is cheap; staging overlaps compute.
template <int MT>
__global__ __launch_bounds__(256) void gemm_bt(
    const unsigned short* __restrict__ A, const unsigned short* __restrict__ BT,
    int N, int mode,
    const float* __restrict__ b0, const float* __restrict__ b1,
    const float* __restrict__ b2,
    unsigned short* __restrict__ o0, unsigned short* __restrict__ o1,
    unsigned short* __restrict__ o2, float* __restrict__ of) {
    __shared__ __align__(16) unsigned short As[2][MT * 32];
    __shared__ __align__(16) unsigned short Bs[2][128 * 32];
    const int K = 1024;
    const int MI = MT / 32;
    int t = threadIdx.x;
    int mBase = blockIdx.x * MT;
    int nBase = blockIdx.y * 128;
    int w = t >> 6, lane = t & 63, l15 = lane & 15, quad = lane >> 4;
    int wm = (w & 1) * (MT / 2), wn = (w >> 1) * 64;
    floatx4 acc[MI][4];
#pragma unroll
    for (int i = 0; i < MI; i++)
#pragma unroll
        for (int j = 0; j < 4; j++) acc[i][j] = (floatx4){0.f, 0.f, 0.f, 0.f};

    int arow = t >> 2, aseg = (t & 3) * 8;
    // prologue: stage k0=0 -> buf 0
#pragma unroll
    for (int i = 0; i < MT / 64; i++)
        async_copy16(&A[(size_t)(mBase + i * 64 + arow) * K + aseg],
                     &As[0][(i * 64 + arow) * 32 + aseg]);
#pragma unroll
    for (int i = 0; i < 2; i++)
        async_copy16(&BT[(size_t)(nBase + i * 64 + arow) * K + aseg],
                     &Bs[0][(i * 64 + arow) * 32 + aseg]);

    for (int k0 = 0; k0 < K; k0 += 32) {
        int cur = (k0 >> 5) & 1;
        __syncthreads();   // drains copies for buf cur (issued one step ago);
                           // all waves finished reading buf cur^1
        if (k0 + 32 < K) {
            int nb = cur ^ 1, kn = k0 + 32;
#pragma unroll
            for (int i = 0; i < MT / 64; i++)
                async_copy16(&A[(size_t)(mBase + i * 64 + arow) * K + kn + aseg],
                             &As[nb][(i * 64 + arow) * 32 + aseg]);
#pragma unroll
            for (int i = 0; i < 2; i++)
                async_copy16(&BT[(size_t)(nBase + i * 64 + arow) * K + kn + aseg],
                             &Bs[nb][(i * 64 + arow) * 32 + aseg]);
        }
        short8 af[MI], bfr[4];
#pragma unroll
        for (int mi = 0; mi < MI; mi++)
            af[mi] = *reinterpret_cast<const short8*>(&As[cur][(wm + mi * 16 + l15) * 32 + quad * 8]);
#pragma unroll
        for (int ni = 0; ni < 4; ni++)
            bfr[ni] = *reinterpret_cast<const short8*>(&Bs[cur][(wn + ni * 16 + l15) * 32 + quad * 8]);
        __builtin_amdgcn_s_setprio(1);
#pragma unroll
        for (int mi = 0; mi < MI; mi++)
#pragma unroll
            for (int ni = 0; ni < 4; ni++)
                acc[mi][ni] = __builtin_amdgcn_mfma_f32_16x16x32_bf16(af[mi], bfr[ni], acc[mi][ni], 0, 0, 0);
        __builtin_amdgcn_s_setprio(0);
    }

#pragma unroll
    for (int mi = 0; mi < MI; mi++) {
        int rowB = mBase + wm + mi * 16 + quad * 4;
#pragma unroll
        for (int ni = 0; ni < 4; ni++) {
            int col = nBase + wn + ni * 16 + l15;
            if (mode == 0) {
                float bias = b0[col];
#pragma unroll
                for (int r = 0; r < 4; r++) {
                    of[(size_t)(rowB + r) * N + col] = acc[mi][ni][r] + bias;
                }
            } else {
                int mat = col >> 10, nn = col & 1023;
                int h = nn >> 6, d = nn & 63;
                int b = rowB >> 11, sidx = rowB & 2047;
                if (mat == 2) {
                    float bv = b2[nn];
                    int jj = sidx & 63;                 // multiple of 4
                    size_t rowOff = ((size_t)((b * NHEADS + h) * 64 + d)) * S_LEN +
                                    (sidx & ~63);
#pragma unroll
                    for (int r = 0; r < 4; r++) {
                        int j2 = jj + r;
                        int jt = j2 >> 4;
                        int u = (jt >> 1) * 32 + ((j2 & 15) >> 2) * 8 + (jt & 1) * 4 + (j2 & 3);
                        o2[rowOff + u] = f2bf(acc[mi][ni][r] + bv);
                    }
                } else {
                    const float* bias  = (mat == 0) ? b0 : b1;
                    unsigned short* op = (mat == 0) ? o0 : o1;
                    float bv = bias[nn];
                    float scl = (mat == 0) ? 0.18033688f : 1.0f;  // dk^-0.5 * log2e
#pragma unroll
                    for (int r = 0; r < 4; r++) {
                        float cv = (acc[mi][ni][r] + bv) * scl;
                        op[(((size_t)b * NHEADS + h) * S_LEN + (sidx + r)) * 64 + d] = f2bf(cv);
                    }
                }
            }
        }
    }
}

// ---------------- flash attention, oscillatory coherence ------------------------
// grid = 256 blocks (1 per CU), 1024 thr (16 waves x 16 Q-rows = 256 Q-rows/block).
// XCD-swizzled. Register-P (swapped QK^T, sigma'd V) + cos/sin staged to LDS.
// R20: 4-deep buffers, barrier only at even kt (16 barriers instead of 32);
// staging for kt+2 and kt+3 issued right after the even-kt barrier.
__global__ __launch_bounds__(1024) void attn_kernel(
    const unsigned short* __restrict__ Qg, const unsigned short* __restrict__ Kg,
    const unsigned short* __restrict__ VTg,
    const float* __restrict__ cosP, const float* __restrict__ sinP,
    const float* __restrict__ alpha, unsigned short* __restrict__ ctx) {
    __shared__ __align__(16) unsigned short KsB[4][64 * 64];   // 32 KB
    __shared__ __align__(16) unsigned short VtB[4][64 * 64];   // 32 KB
    __shared__ __align__(16) float csB[4][128];                // 2 KB

    int x = blockIdx.x;                     // 0..255
    int bh = (x & 7) * 4 + (x >> 6);        // XCD (x%8) owns 4 consecutive bh groups
    int qt = (x >> 3) & 7;                  // 8 Q-tiles of 256 rows per bh
    int t = threadIdx.x, w = t >> 6, lane = t & 63, l15 = lane & 15, quad = lane >> 4;
    int m0 = qt * 256 + w * 16;
    size_t base = (size_t)bh * (S_LEN * 64);
    size_t phBase = (size_t)bh * S_LEN;
    const float L2E = 1.44269504f;

    // staging geometry: threads 0..511 own K bytes [16t,16t+16), 512..1023 own V
    int th = t & 511;
    int sj = th >> 3, sg = th & 7;
    int srot = ((sg - (sj & 7)) & 7) * 8;   // shorts: un-rotated global column
    bool stK = (t < 512);

    // Q frags; Q pre-scaled by 0.125*L2E. Used as B-operand (col = Q-row = l15).
    short8 qf[2];
#pragma unroll
    for (int c = 0; c < 2; c++)
        qf[c] = *reinterpret_cast<const short8*>(
            &Qg[base + (size_t)(m0 + l15) * 64 + c * 32 + quad * 8]);

    float alph = alpha[bh & 15] * L2E;
    // per-lane coherence coefficients for this thread's Q-row (m0 + l15)
    float ci = alph * cosP[phBase + m0 + l15];
    float si = alph * sinP[phBase + m0 + l15];
    float2v ci2 = (float2v){ci, ci}, si2 = (float2v){si, si};

    {   // prologue: stage tiles 0 and 1 -> bufs 0,1
#pragma unroll
        for (int t0 = 0; t0 < 2; t0++) {
            if (stK) async_copy16(&Kg[base + (size_t)(t0 * 64 + sj) * 64 + srot], &KsB[t0][th * 8]);
            else     async_copy16(&VTg[base + (size_t)sj * S_LEN + t0 * 64 + srot], &VtB[t0][th * 8]);
            if (w == 4)      async_copy4(&cosP[phBase + t0 * 64 + lane], &csB[t0][lane]);
            else if (w == 5) async_copy4(&sinP[phBase + t0 * 64 + lane], &csB[t0][64 + lane]);
        }
    }

    floatx4 oacc[4], lacc;
#pragma unroll
    for (int tt = 0; tt < 4; tt++) oacc[tt] = (floatx4){0.f, 0.f, 0.f, 0.f};
    lacc = (floatx4){0.f, 0.f, 0.f, 0.f};
    const short8 ones8 = {(short)0x3F80, (short)0x3F80, (short)0x3F80, (short)0x3F80,
                          (short)0x3F80, (short)0x3F80, (short)0x3F80, (short)0x3F80};

    // frag-read rotation
    int rot = l15 & 7;
    int cb0 = 16 * ((quad + rot) & 7);        // bytes, k-chunk c=0
    int cb1 = 16 * ((quad + 4 + rot) & 7);    // bytes, k-chunk c=1

    for (int kt = 0; kt < 32; kt++) {
        int p = kt & 3;
        if ((kt & 1) == 0) {
            __syncthreads();   // drains copies issued at kt-2 (tiles kt, kt+1);
                               // all waves done with iters <= kt-1
#pragma unroll
            for (int d = 2; d <= 3; d++) {
                int kn = kt + d;
                if (kn < 32) {
                    int pn = kn & 3;
                    if (stK) async_copy16(&Kg[base + (size_t)(kn * 64 + sj) * 64 + srot], &KsB[pn][th * 8]);
                    else     async_copy16(&VTg[base + (size_t)sj * S_LEN + kn * 64 + srot], &VtB[pn][th * 8]);
                    if (w == 4)      async_copy4(&cosP[phBase + kn * 64 + lane], &csB[pn][lane]);
                    else if (w == 5) async_copy4(&sinP[phBase + kn * 64 + lane], &csB[pn][64 + lane]);
                }
            }
        }

        // QK^T swapped: st[jt][r] = score[K-tok kt*64+jt*16+quad*4+r][Q-row m0+l15]
        floatx4 st[4];
        __builtin_amdgcn_s_setprio(1);
#pragma unroll
        for (int jt = 0; jt < 4; jt++) {
            const char* kr = (const char*)&KsB[p][(jt * 16 + l15) * 64];
            short8 kf0 = *reinterpret_cast<const short8*>(kr + cb0);
            short8 kf1 = *reinterpret_cast<const short8*>(kr + cb1);
            floatx4 s = (floatx4){0.f, 0.f, 0.f, 0.f};
            s = __builtin_amdgcn_mfma_f32_16x16x32_bf16(kf0, qf[0], s, 0, 0, 0);
            s = __builtin_amdgcn_mfma_f32_16x16x32_bf16(kf1, qf[1], s, 0, 0, 0);
            st[jt] = s;
        }
        __builtin_amdgcn_s_setprio(0);

        // P = exp2(st + ci*cos(phi_j) + si*sin(phi_j)), packed in-register.
        // cos/sin from LDS: quad-uniform float4 reads (broadcast, conflict-free).
        union PW { unsigned int u[4]; short8 s8; };
        PW P0, P1;
#pragma unroll
        for (int jt = 0; jt < 4; jt++) {
            float4 cj4 = *reinterpret_cast<const float4*>(&csB[p][jt * 16 + quad * 4]);
            float4 sj4 = *reinterpret_cast<const float4*>(&csB[p][64 + jt * 16 + quad * 4]);
            float2v st01 = (float2v){st[jt][0], st[jt][1]};
            float2v st23 = (float2v){st[jt][2], st[jt][3]};
            float2v c01 = (float2v){cj4.x, cj4.y}, c23 = (float2v){cj4.z, cj4.w};
            float2v s01 = (float2v){sj4.x, sj4.y}, s23 = (float2v){sj4.z, sj4.w};
            float2v a01 = si2 * s01 + (ci2 * c01 + st01);
            float2v a23 = si2 * s23 + (ci2 * c23 + st23);
            unsigned int wA = pack2_bf16(__builtin_amdgcn_exp2f(a01.y),
                                         __builtin_amdgcn_exp2f(a01.x));
            unsigned int wB = pack2_bf16(__builtin_amdgcn_exp2f(a23.y),
                                         __builtin_amdgcn_exp2f(a23.x));
            if (jt == 0)      { P0.u[0] = wA; P0.u[1] = wB; }
            else if (jt == 1) { P0.u[2] = wA; P0.u[3] = wB; }
            else if (jt == 2) { P1.u[0] = wA; P1.u[1] = wB; }
            else              { P1.u[2] = wA; P1.u[3] = wB; }
        }

        // O += P @ V; l += P @ ones   (V stored with matching sigma)
        __builtin_amdgcn_s_setprio(1);
#pragma unroll
        for (int c = 0; c < 2; c++) {
            short8 pf = c ? P1.s8 : P0.s8;
            int cb = c ? cb1 : cb0;
#pragma unroll
            for (int tt = 0; tt < 4; tt++) {
                const char* vr = (const char*)&VtB[p][(tt * 16 + l15) * 64];
                short8 vf = *reinterpret_cast<const short8*>(vr + cb);
                oacc[tt] = __builtin_amdgcn_mfma_f32_16x16x32_bf16(pf, vf, oacc[tt], 0, 0, 0);
            }
            lacc = __builtin_amdgcn_mfma_f32_16x16x32_bf16(pf, ones8, lacc, 0, 0, 0);
        }
        __builtin_amdgcn_s_setprio(0);
    }

    // epilogue: normalize rows by l and write ctx[b][s][h*64+d]
    int b = bh >> 4, h = bh & 15;
    float inv[4];
#pragma unroll
    for (int r = 0; r < 4; r++) inv[r] = 1.0f / lacc[r];
#pragma unroll
    for (int tt = 0; tt < 4; tt++)
#pragma unroll
        for (int r = 0; r < 4; r++) {
            int srow = m0 + quad * 4 + r;
            ctx[((size_t)(b * S_LEN + srow)) * 1024 + h * 64 + tt * 16 + l15] =
                f2bf(oacc[tt][r] * inv[r]);
        }
}

extern "C" void kernel_launch(void* const* d_in, const int* in_sizes, int n_in,
                              void* d_out, int out_size, void* d_ws, size_t ws_size,
                              hipStream_t stream) {
    const float* x     = (const float*)d_in[0];
    const float* Wq    = (const float*)d_in[1];
    const float* bq    = (const float*)d_in[2];
    const float* Wk    = (const float*)d_in[3];
    const float* bk    = (const float*)d_in[4];
    const float* Wv    = (const float*)d_in[5];
    const float* bv    = (const float*)d_in[6];
    const float* Wo    = (const float*)d_in[7];
    const float* bo    = (const float*)d_in[8];
    const float* Wp    = (const float*)d_in[9];
    const float* bp    = (const float*)d_in[10];
    const float* alpha = (const float*)d_in[11];
    float* out = (float*)d_out;

    const size_t MB = 1048576;
    char* ws = (char*)d_ws;
    unsigned short* WT   = (unsigned short*)(ws);             // 3072x1024 bf16
    unsigned short* WoT  = (unsigned short*)(ws + 6 * MB);    // 1024x1024 bf16
    unsigned short* xb   = (unsigned short*)(ws + 8 * MB);    // (B,S,D) bf16
    unsigned short* ctx  = (unsigned short*)(ws + 8 * MB);    // aliases xb
    unsigned short* Qw   = (unsigned short*)(ws + 16 * MB);   // (B,H,S,dk), pre-scaled
    unsigned short* Kw   = (unsigned short*)(ws + 24 * MB);   // (B,H,S,dk)
    unsigned short* VTg  = (unsigned short*)(ws + 32 * MB);   // (B,H,dk,S) sigma-interleaved
    float* cosP          = (float*)(ws + 40 * MB);
    float* sinP          = (float*)(ws + 40 * MB + 262144);

    prep_kernel<<<dim3(5120), dim3(256), 0, stream>>>(
        x, Wp, bp, Wq, Wk, Wv, Wo,
        WT, WT + 1048576, WT + 2097152, WoT, cosP, sinP, xb);
    gemm_bt<128><<<dim3(32, 24), dim3(256), 0, stream>>>(
        xb, WT, 3072, 1, bq, bk, bv, Qw, Kw, VTg, (float*)nullptr);
    attn_kernel<<<dim3(256), dim3(1024), 0, stream>>>(
        Qw, Kw, VTg, cosP, sinP, alpha, ctx);
    gemm_bt<64><<<dim3(64, 8), dim3(256), 0, stream>>>(
        ctx, WoT, 1024, 0, bo, bo, bo,
        (unsigned short*)nullptr, (unsigned short*)nullptr,
        (unsigned short*)nullptr, out);
}